// Round 5
// baseline (553.283 us; speedup 1.0000x reference)
//
#include <hip/hip_runtime.h>
#include <cstdint>
#include <cstddef>

#define N_NODES 65536
#define N_EDGES 1048576
#define E_TOT   (N_EDGES + N_NODES)
#define NSLICE  8192            // N_NODES / 8 XCD slices
#define SCHUNK  ((E_TOT + 31) / 32)

using short8  = __attribute__((ext_vector_type(8))) short;
using floatx4 = __attribute__((ext_vector_type(4))) float;

// split fp32 -> bf16 hi (RTN) + bf16 lo (trunc of residual)
__device__ inline void split_bf16(float a, short& hi, short& lo) {
    unsigned u  = __float_as_uint(a);
    unsigned hr = (u + 0x7fffu + ((u >> 16) & 1u)) >> 16;
    float    hf = __uint_as_float(hr << 16);
    hi = (short)hr;
    float    lf = a - hf;
    lo = (short)(__float_as_uint(lf) >> 16);
}

// ---------------- preprocessing ----------------

__global__ void k_init_deg(int* __restrict__ deg) {
    int n = blockIdx.x * 256 + threadIdx.x;
    deg[n] = 1;  // self loop
}

// XCD-sliced histogram: block b handles dst slice (b&7); blocks with equal b&7
// land on the same XCD under round-robin dispatch -> deg lines stay XCD-local.
__global__ void k_hist(const int* __restrict__ dst, int* __restrict__ deg) {
    int g   = blockIdx.x & 7;
    int blk = blockIdx.x >> 3;
    int lo = g * NSLICE, hi = lo + NSLICE;
    int e0 = blk * SCHUNK;
    int e1 = e0 + SCHUNK; if (e1 > N_EDGES) e1 = N_EDGES;
    for (int e = e0 + threadIdx.x; e < e1; e += 256) {
        int d = dst[e];
        if (d >= lo && d < hi) atomicAdd(&deg[d], 1);
    }
}

__global__ __launch_bounds__(256) void k_scan1(const int* __restrict__ deg, int* __restrict__ off,
                                               int* __restrict__ bsum) {
    __shared__ int sb[256];
    int tid = threadIdx.x;
    int g = blockIdx.x * 256 + tid;
    int v = deg[g];
    sb[tid] = v;
    __syncthreads();
    #pragma unroll
    for (int s = 1; s < 256; s <<= 1) {
        int t = (tid >= s) ? sb[tid - s] : 0;
        __syncthreads();
        sb[tid] += t;
        __syncthreads();
    }
    off[g] = sb[tid] - v;
    if (tid == 255) bsum[blockIdx.x] = sb[255];
}

__global__ __launch_bounds__(256) void k_scan2(int* __restrict__ bsum) {
    __shared__ int sb[256];
    int tid = threadIdx.x;
    int v = bsum[tid];
    sb[tid] = v;
    __syncthreads();
    #pragma unroll
    for (int s = 1; s < 256; s <<= 1) {
        int t = (tid >= s) ? sb[tid - s] : 0;
        __syncthreads();
        sb[tid] += t;
        __syncthreads();
    }
    bsum[tid] = sb[tid] - v;
}

__global__ __launch_bounds__(256) void k_scan3(const int* __restrict__ deg, int* __restrict__ off,
                                               int* __restrict__ cursor, float* __restrict__ dis,
                                               const int* __restrict__ bsum) {
    int tid = threadIdx.x;
    int g = blockIdx.x * 256 + tid;
    int o = off[g] + bsum[blockIdx.x];
    off[g] = o;
    cursor[g] = o;
    dis[g] = rsqrtf((float)deg[g]);
    if (g == 0) off[N_NODES] = E_TOT;
}

// XCD-sliced counting-sort scatter: block b handles dst slice (b&7).
// ssort positions for a slice are contiguous -> written by one XCD -> no line ping-pong.
__global__ void k_scatter(const int* __restrict__ src, const int* __restrict__ dst,
                          int* __restrict__ cursor, int* __restrict__ ssort) {
    int g   = blockIdx.x & 7;
    int blk = blockIdx.x >> 3;
    int lo = g * NSLICE, hi = lo + NSLICE;
    int e0 = blk * SCHUNK;
    int e1 = e0 + SCHUNK; if (e1 > E_TOT) e1 = E_TOT;
    for (int e = e0 + threadIdx.x; e < e1; e += 256) {
        int s, d;
        if (e < N_EDGES) { s = src[e]; d = dst[e]; }
        else             { s = d = e - N_EDGES; }
        if (d >= lo && d < hi) {
            int pos = atomicAdd(&cursor[d], 1);
            ssort[pos] = s;
        }
    }
}

// ---------------- W -> fragment-ordered bf16 hi/lo ----------------

__global__ void k_convw(const float* __restrict__ W, int K, int N,
                        short* __restrict__ Bh, short* __restrict__ Bl) {
    int g = blockIdx.x * 256 + threadIdx.x;
    int total = (N / 16) * (K / 32) * 64;
    if (g >= total) return;
    int lane = g & 63;
    int kt = (g >> 6) % (K / 32);
    int nt = (g >> 6) / (K / 32);
    int n = nt * 16 + (lane & 15);
    int kbase = kt * 32 + (lane >> 4) * 8;
    #pragma unroll
    for (int j = 0; j < 8; ++j) {
        short h, l;
        split_bf16(W[(size_t)(kbase + j) * N + n], h, l);
        Bh[(size_t)g * 8 + j] = h;
        Bl[(size_t)g * 8 + j] = l;
    }
}

// ---------------- split-bf16 MFMA GEMM: C[M,N] = A[M,K] @ W ----------------

template <int K, int N, bool ACT, bool SCALE_OUT>
__global__ __launch_bounds__(256) void k_mm(const float* __restrict__ A,
                                            const short* __restrict__ Bh, const short* __restrict__ Bl,
                                            const float* __restrict__ bias, const float* __restrict__ dis,
                                            float* __restrict__ C) {
    constexpr int NT = N / 16;
    constexpr int KT = K / 32;
    __shared__ short Ah[4 * 64 * 8];
    __shared__ short Al[4 * 64 * 8];
    int tid = threadIdx.x;
    int wave = tid >> 6, lane = tid & 63;
    int quad = lane >> 4, col = lane & 15;
    size_t row0 = (size_t)blockIdx.x * 64;

    floatx4 acc[NT];
    #pragma unroll
    for (int t = 0; t < NT; ++t) acc[t] = (floatx4)0.0f;

    int srow = tid >> 2;
    int sdst = ((srow >> 4) * 64 + (srow & 15) + ((tid & 3) << 4)) * 8;
    const float* arow = A + (row0 + srow) * K + (tid & 3) * 8;

    for (int kt = 0; kt < KT; ++kt) {
        float4 a0 = *(const float4*)(arow + kt * 32);
        float4 a1 = *(const float4*)(arow + kt * 32 + 4);
        float av[8] = {a0.x, a0.y, a0.z, a0.w, a1.x, a1.y, a1.z, a1.w};
        short h[8], l[8];
        #pragma unroll
        for (int j = 0; j < 8; ++j) split_bf16(av[j], h[j], l[j]);
        __syncthreads();
        *(short8*)(&Ah[sdst]) = *(short8*)h;
        *(short8*)(&Al[sdst]) = *(short8*)l;
        __syncthreads();
        short8 afh = *(short8*)(&Ah[(wave * 64 + lane) * 8]);
        short8 afl = *(short8*)(&Al[(wave * 64 + lane) * 8]);
        #pragma unroll
        for (int nt = 0; nt < NT; ++nt) {
            size_t bi = ((size_t)(nt * KT + kt) * 64 + lane);
            short8 bfh = ((const short8*)Bh)[bi];
            short8 bfl = ((const short8*)Bl)[bi];
            acc[nt] = __builtin_amdgcn_mfma_f32_16x16x32_bf16(afh, bfh, acc[nt], 0, 0, 0);
            acc[nt] = __builtin_amdgcn_mfma_f32_16x16x32_bf16(afh, bfl, acc[nt], 0, 0, 0);
            acc[nt] = __builtin_amdgcn_mfma_f32_16x16x32_bf16(afl, bfh, acc[nt], 0, 0, 0);
        }
    }

    size_t rbase = row0 + wave * 16 + quad * 4;
    if (!ACT) {
        float4 d4 = make_float4(1.f, 1.f, 1.f, 1.f);
        if (SCALE_OUT) d4 = *(const float4*)(dis + rbase);
        float dr[4] = {d4.x, d4.y, d4.z, d4.w};
        #pragma unroll
        for (int nt = 0; nt < NT; ++nt)
            #pragma unroll
            for (int r = 0; r < 4; ++r)
                C[(rbase + r) * N + nt * 16 + col] = acc[nt][r] * dr[r];
    } else {
        float bv[NT];
        #pragma unroll
        for (int nt = 0; nt < NT; ++nt) bv[nt] = bias[nt * 16 + col];
        float mr[4] = {0.f, 0.f, 0.f, 0.f};
        #pragma unroll
        for (int nt = 0; nt < NT; ++nt)
            #pragma unroll
            for (int r = 0; r < 4; ++r) {
                float v = fmaxf(acc[nt][r] + bv[nt], 0.0f);
                acc[nt][r] = v;
                mr[r] = fmaxf(mr[r], v);
            }
        #pragma unroll
        for (int mask = 1; mask < 16; mask <<= 1)
            #pragma unroll
            for (int r = 0; r < 4; ++r) mr[r] = fmaxf(mr[r], __shfl_xor(mr[r], mask, 64));
        float sr[4] = {0.f, 0.f, 0.f, 0.f};
        #pragma unroll
        for (int nt = 0; nt < NT; ++nt)
            #pragma unroll
            for (int r = 0; r < 4; ++r) {
                float t = __expf(acc[nt][r] - mr[r]);
                acc[nt][r] = t;
                sr[r] += t;
            }
        #pragma unroll
        for (int mask = 1; mask < 16; mask <<= 1)
            #pragma unroll
            for (int r = 0; r < 4; ++r) sr[r] += __shfl_xor(sr[r], mask, 64);
        float inv[4];
        #pragma unroll
        for (int r = 0; r < 4; ++r) inv[r] = 1.0f / sr[r];
        #pragma unroll
        for (int nt = 0; nt < NT; ++nt)
            #pragma unroll
            for (int r = 0; r < 4; ++r)
                C[(rbase + r) * N + nt * 16 + col] = acc[nt][r] * inv[r];
    }
}

// ---------------- aggregation, DOUT=128: half-wave x float4 per edge, 8 gathers in flight ----------------

template <bool SCALE_SRC, bool ACT>
__global__ __launch_bounds__(256) void k_agg128(const float* __restrict__ h, const int* __restrict__ off,
                                                const int* __restrict__ ss, const float* __restrict__ dis,
                                                const float* __restrict__ bias, float* __restrict__ out) {
    int lane = threadIdx.x & 63;
    int half = lane >> 5;
    int li = lane & 31;
    int c0 = 4 * li;
    int n = blockIdx.x * 4 + (threadIdx.x >> 6);
    int e0 = off[n], e1 = off[n + 1];
    int e = e0;
    float4 acc = make_float4(0.f, 0.f, 0.f, 0.f);

    // 16 edges per iter -> 8 outstanding dwordx4 gathers per lane
    for (; e + 16 <= e1; e += 16) {
        int s0 = ss[e + 0 + half];
        int s1 = ss[e + 2 + half];
        int s2 = ss[e + 4 + half];
        int s3 = ss[e + 6 + half];
        int s4 = ss[e + 8 + half];
        int s5 = ss[e + 10 + half];
        int s6 = ss[e + 12 + half];
        int s7 = ss[e + 14 + half];
        float4 v0 = *(const float4*)(h + (size_t)s0 * 128 + c0);
        float4 v1 = *(const float4*)(h + (size_t)s1 * 128 + c0);
        float4 v2 = *(const float4*)(h + (size_t)s2 * 128 + c0);
        float4 v3 = *(const float4*)(h + (size_t)s3 * 128 + c0);
        float4 v4 = *(const float4*)(h + (size_t)s4 * 128 + c0);
        float4 v5 = *(const float4*)(h + (size_t)s5 * 128 + c0);
        float4 v6 = *(const float4*)(h + (size_t)s6 * 128 + c0);
        float4 v7 = *(const float4*)(h + (size_t)s7 * 128 + c0);
        float w0 = SCALE_SRC ? dis[s0] : 1.0f;
        float w1 = SCALE_SRC ? dis[s1] : 1.0f;
        float w2 = SCALE_SRC ? dis[s2] : 1.0f;
        float w3 = SCALE_SRC ? dis[s3] : 1.0f;
        float w4 = SCALE_SRC ? dis[s4] : 1.0f;
        float w5 = SCALE_SRC ? dis[s5] : 1.0f;
        float w6 = SCALE_SRC ? dis[s6] : 1.0f;
        float w7 = SCALE_SRC ? dis[s7] : 1.0f;
        acc.x = fmaf(w0, v0.x, acc.x); acc.y = fmaf(w0, v0.y, acc.y);
        acc.z = fmaf(w0, v0.z, acc.z); acc.w = fmaf(w0, v0.w, acc.w);
        acc.x = fmaf(w1, v1.x, acc.x); acc.y = fmaf(w1, v1.y, acc.y);
        acc.z = fmaf(w1, v1.z, acc.z); acc.w = fmaf(w1, v1.w, acc.w);
        acc.x = fmaf(w2, v2.x, acc.x); acc.y = fmaf(w2, v2.y, acc.y);
        acc.z = fmaf(w2, v2.z, acc.z); acc.w = fmaf(w2, v2.w, acc.w);
        acc.x = fmaf(w3, v3.x, acc.x); acc.y = fmaf(w3, v3.y, acc.y);
        acc.z = fmaf(w3, v3.z, acc.z); acc.w = fmaf(w3, v3.w, acc.w);
        acc.x = fmaf(w4, v4.x, acc.x); acc.y = fmaf(w4, v4.y, acc.y);
        acc.z = fmaf(w4, v4.z, acc.z); acc.w = fmaf(w4, v4.w, acc.w);
        acc.x = fmaf(w5, v5.x, acc.x); acc.y = fmaf(w5, v5.y, acc.y);
        acc.z = fmaf(w5, v5.z, acc.z); acc.w = fmaf(w5, v5.w, acc.w);
        acc.x = fmaf(w6, v6.x, acc.x); acc.y = fmaf(w6, v6.y, acc.y);
        acc.z = fmaf(w6, v6.z, acc.z); acc.w = fmaf(w6, v6.w, acc.w);
        acc.x = fmaf(w7, v7.x, acc.x); acc.y = fmaf(w7, v7.y, acc.y);
        acc.z = fmaf(w7, v7.z, acc.z); acc.w = fmaf(w7, v7.w, acc.w);
    }
    for (; e + 2 <= e1; e += 2) {
        int s = ss[e + half];
        float4 v = *(const float4*)(h + (size_t)s * 128 + c0);
        float w = SCALE_SRC ? dis[s] : 1.0f;
        acc.x = fmaf(w, v.x, acc.x); acc.y = fmaf(w, v.y, acc.y);
        acc.z = fmaf(w, v.z, acc.z); acc.w = fmaf(w, v.w, acc.w);
    }
    if (e < e1) {  // odd tail: only half 0 contributes
        int s = ss[e];
        float4 v = *(const float4*)(h + (size_t)s * 128 + c0);
        float w = (half == 0) ? (SCALE_SRC ? dis[s] : 1.0f) : 0.0f;
        acc.x = fmaf(w, v.x, acc.x); acc.y = fmaf(w, v.y, acc.y);
        acc.z = fmaf(w, v.z, acc.z); acc.w = fmaf(w, v.w, acc.w);
    }

    acc.x += __shfl_xor(acc.x, 32, 64);
    acc.y += __shfl_xor(acc.y, 32, 64);
    acc.z += __shfl_xor(acc.z, 32, 64);
    acc.w += __shfl_xor(acc.w, 32, 64);

    float dn = dis[n];
    acc.x *= dn; acc.y *= dn; acc.z *= dn; acc.w *= dn;

    if (ACT) {
        float4 b4 = *(const float4*)(bias + c0);
        float v[4] = {fmaxf(acc.x + b4.x, 0.f), fmaxf(acc.y + b4.y, 0.f),
                      fmaxf(acc.z + b4.z, 0.f), fmaxf(acc.w + b4.w, 0.f)};
        float m = fmaxf(fmaxf(v[0], v[1]), fmaxf(v[2], v[3]));
        #pragma unroll
        for (int mask = 16; mask > 0; mask >>= 1) m = fmaxf(m, __shfl_xor(m, mask, 64));
        float sum = 0.f;
        #pragma unroll
        for (int j = 0; j < 4; ++j) {
            v[j] = __expf(v[j] - m);
            sum += v[j];
        }
        #pragma unroll
        for (int mask = 16; mask > 0; mask >>= 1) sum += __shfl_xor(sum, mask, 64);
        float inv = 1.0f / sum;
        if (half == 0)
            *(float4*)(out + (size_t)n * 128 + c0) = make_float4(v[0] * inv, v[1] * inv, v[2] * inv, v[3] * inv);
    } else {
        if (half == 0)
            *(float4*)(out + (size_t)n * 128 + c0) = acc;
    }
}

// ---------------- aggregation, DOUT=64: quarter-wave x float4 per edge ----------------

__global__ __launch_bounds__(256) void k_agg64(const float* __restrict__ h, const int* __restrict__ off,
                                               const int* __restrict__ ss, const float* __restrict__ dis,
                                               const float* __restrict__ bias, float* __restrict__ out) {
    int lane = threadIdx.x & 63;
    int sub = lane >> 4;
    int li = lane & 15;
    int c0 = 4 * li;
    int n = blockIdx.x * 4 + (threadIdx.x >> 6);
    int e0 = off[n], e1 = off[n + 1];
    int e = e0;
    float4 acc = make_float4(0.f, 0.f, 0.f, 0.f);

    for (; e + 16 <= e1; e += 16) {
        int s0 = ss[e + sub];
        int s1 = ss[e + 4 + sub];
        int s2 = ss[e + 8 + sub];
        int s3 = ss[e + 12 + sub];
        float4 v0 = *(const float4*)(h + (size_t)s0 * 64 + c0);
        float4 v1 = *(const float4*)(h + (size_t)s1 * 64 + c0);
        float4 v2 = *(const float4*)(h + (size_t)s2 * 64 + c0);
        float4 v3 = *(const float4*)(h + (size_t)s3 * 64 + c0);
        acc.x += v0.x + v1.x + v2.x + v3.x;
        acc.y += v0.y + v1.y + v2.y + v3.y;
        acc.z += v0.z + v1.z + v2.z + v3.z;
        acc.w += v0.w + v1.w + v2.w + v3.w;
    }
    for (; e + 4 <= e1; e += 4) {
        int s = ss[e + sub];
        float4 v = *(const float4*)(h + (size_t)s * 64 + c0);
        acc.x += v.x; acc.y += v.y; acc.z += v.z; acc.w += v.w;
    }
    int rem = e1 - e;
    if (rem > 0) {
        int idx = e + sub;
        if (idx >= e1) idx = e1 - 1;
        int s = ss[idx];
        float4 v = *(const float4*)(h + (size_t)s * 64 + c0);
        float w = (sub < rem) ? 1.0f : 0.0f;
        acc.x = fmaf(w, v.x, acc.x); acc.y = fmaf(w, v.y, acc.y);
        acc.z = fmaf(w, v.z, acc.z); acc.w = fmaf(w, v.w, acc.w);
    }

    #pragma unroll
    for (int mask = 32; mask >= 16; mask >>= 1) {
        acc.x += __shfl_xor(acc.x, mask, 64);
        acc.y += __shfl_xor(acc.y, mask, 64);
        acc.z += __shfl_xor(acc.z, mask, 64);
        acc.w += __shfl_xor(acc.w, mask, 64);
    }

    float dn = dis[n];
    float4 b4 = *(const float4*)(bias + c0);
    float v[4] = {fmaxf(fmaf(acc.x, dn, b4.x), 0.f), fmaxf(fmaf(acc.y, dn, b4.y), 0.f),
                  fmaxf(fmaf(acc.z, dn, b4.z), 0.f), fmaxf(fmaf(acc.w, dn, b4.w), 0.f)};
    float m = fmaxf(fmaxf(v[0], v[1]), fmaxf(v[2], v[3]));
    #pragma unroll
    for (int mask = 8; mask > 0; mask >>= 1) m = fmaxf(m, __shfl_xor(m, mask, 64));
    float sum = 0.f;
    #pragma unroll
    for (int j = 0; j < 4; ++j) {
        v[j] = __expf(v[j] - m);
        sum += v[j];
    }
    #pragma unroll
    for (int mask = 8; mask > 0; mask >>= 1) sum += __shfl_xor(sum, mask, 64);
    float inv = 1.0f / sum;
    if (sub == 0)
        *(float4*)(out + (size_t)n * 64 + c0) = make_float4(v[0] * inv, v[1] * inv, v[2] * inv, v[3] * inv);
}

// ---------------- launch ----------------

extern "C" void kernel_launch(void* const* d_in, const int* in_sizes, int n_in,
                              void* d_out, int out_size, void* d_ws, size_t ws_size,
                              hipStream_t stream) {
    const float* x  = (const float*)d_in[0];
    const int*   ei = (const int*)d_in[1];
    const float* W1 = (const float*)d_in[2];
    const float* b1 = (const float*)d_in[3];
    const float* W2 = (const float*)d_in[4];
    const float* b2 = (const float*)d_in[5];
    const float* W3 = (const float*)d_in[6];
    const float* b3 = (const float*)d_in[7];
    const int* srcE = ei;
    const int* dstE = ei + N_EDGES;

    char* p = (char*)d_ws;
    auto carve = [&](size_t bytes) {
        char* q = p;
        p += (bytes + 255) & ~(size_t)255;
        return q;
    };
    int*   deg   = (int*)carve(sizeof(int) * N_NODES);
    int*   off   = (int*)carve(sizeof(int) * (N_NODES + 1));
    int*   cur   = (int*)carve(sizeof(int) * N_NODES);
    float* dis   = (float*)carve(sizeof(float) * N_NODES);
    int*   bsum  = (int*)carve(sizeof(int) * 256);
    int*   ssort = (int*)carve(sizeof(int) * E_TOT);
    short* w1h   = (short*)carve(sizeof(short) * 128 * 256);
    short* w1l   = (short*)carve(sizeof(short) * 128 * 256);
    short* w2h   = (short*)carve(sizeof(short) * 256 * 128);
    short* w2l   = (short*)carve(sizeof(short) * 256 * 128);
    short* w3h   = (short*)carve(sizeof(short) * 128 * 64);
    short* w3l   = (short*)carve(sizeof(short) * 128 * 64);
    float* bufA  = (float*)carve(sizeof(float) * (size_t)N_NODES * 256);
    float* bufB  = (float*)carve(sizeof(float) * (size_t)N_NODES * 256);

    k_init_deg<<<N_NODES / 256, 256, 0, stream>>>(deg);
    k_hist<<<256, 256, 0, stream>>>(dstE, deg);
    k_scan1<<<N_NODES / 256, 256, 0, stream>>>(deg, off, bsum);
    k_scan2<<<1, 256, 0, stream>>>(bsum);
    k_scan3<<<N_NODES / 256, 256, 0, stream>>>(deg, off, cur, dis, bsum);
    k_scatter<<<256, 256, 0, stream>>>(srcE, dstE, cur, ssort);
    k_convw<<<(16 * 4 * 64 + 255) / 256, 256, 0, stream>>>(W1, 128, 256, w1h, w1l);
    k_convw<<<(8 * 8 * 64 + 255) / 256, 256, 0, stream>>>(W2, 256, 128, w2h, w2l);
    k_convw<<<(4 * 4 * 64 + 255) / 256, 256, 0, stream>>>(W3, 128, 64, w3h, w3l);

    // layer 1 (agg-first): a0[n] = dis[n] * sum dis[s]*x[s]; x1 = softmax(relu(a0@W1 + b1))
    k_agg128<true, false><<<N_NODES / 4, 256, 0, stream>>>(x, off, ssort, dis, nullptr, bufB);
    k_mm<128, 256, true, false><<<N_NODES / 64, 256, 0, stream>>>(bufB, w1h, w1l, b1, nullptr, bufA);
    // layer 2: h2' = dis .* (x1@W2); x2 = softmax(relu(dis[n]*segsum(h2') + b2))
    k_mm<256, 128, false, true><<<N_NODES / 64, 256, 0, stream>>>(bufA, w2h, w2l, nullptr, dis, bufB);
    k_agg128<false, true><<<N_NODES / 4, 256, 0, stream>>>(bufB, off, ssort, dis, b2, bufA);
    // layer 3: h3' = dis .* (x2@W3); out = softmax(relu(dis[n]*segsum(h3') + b3))
    k_mm<128, 64, false, true><<<N_NODES / 64, 256, 0, stream>>>(bufA, w3h, w3l, nullptr, dis, bufB);
    k_agg64<<<N_NODES / 4, 256, 0, stream>>>(bufB, off, ssort, dis, b3, (float*)d_out);
}

// Round 6
// 483.431 us; speedup vs baseline: 1.1445x; 1.1445x over previous
//
#include <hip/hip_runtime.h>
#include <cstdint>
#include <cstddef>

#define N_NODES 65536
#define N_EDGES 1048576
#define E_TOT   (N_EDGES + N_NODES)
#define NSLICE  8192                    // N_NODES / 8 XCD slices
#define SCHUNK  ((E_TOT + 255) / 256)   // 4352: 256 chunks per slice

using short8  = __attribute__((ext_vector_type(8))) short;
using floatx4 = __attribute__((ext_vector_type(4))) float;

// split fp32 -> bf16 hi (RTN) + bf16 lo (trunc of residual)
__device__ inline void split_bf16(float a, short& hi, short& lo) {
    unsigned u  = __float_as_uint(a);
    unsigned hr = (u + 0x7fffu + ((u >> 16) & 1u)) >> 16;
    float    hf = __uint_as_float(hr << 16);
    hi = (short)hr;
    float    lf = a - hf;
    lo = (short)(__float_as_uint(lf) >> 16);
}

// ---------------- preprocessing ----------------

__global__ void k_init_deg(int* __restrict__ deg) {
    int n = blockIdx.x * 256 + threadIdx.x;
    deg[n] = 1;  // self loop
}

// simple full-grid histogram (was never the bottleneck)
__global__ void k_hist(const int* __restrict__ dst, int* __restrict__ deg) {
    int e = blockIdx.x * 256 + threadIdx.x;
    if (e < N_EDGES) atomicAdd(&deg[dst[e]], 1);
}

__global__ __launch_bounds__(256) void k_scan1(const int* __restrict__ deg, int* __restrict__ off,
                                               int* __restrict__ bsum) {
    __shared__ int sb[256];
    int tid = threadIdx.x;
    int g = blockIdx.x * 256 + tid;
    int v = deg[g];
    sb[tid] = v;
    __syncthreads();
    #pragma unroll
    for (int s = 1; s < 256; s <<= 1) {
        int t = (tid >= s) ? sb[tid - s] : 0;
        __syncthreads();
        sb[tid] += t;
        __syncthreads();
    }
    off[g] = sb[tid] - v;
    if (tid == 255) bsum[blockIdx.x] = sb[255];
}

__global__ __launch_bounds__(256) void k_scan2(int* __restrict__ bsum) {
    __shared__ int sb[256];
    int tid = threadIdx.x;
    int v = bsum[tid];
    sb[tid] = v;
    __syncthreads();
    #pragma unroll
    for (int s = 1; s < 256; s <<= 1) {
        int t = (tid >= s) ? sb[tid - s] : 0;
        __syncthreads();
        sb[tid] += t;
        __syncthreads();
    }
    bsum[tid] = sb[tid] - v;
}

__global__ __launch_bounds__(256) void k_scan3(const int* __restrict__ deg, int* __restrict__ off,
                                               int* __restrict__ cursor, float* __restrict__ dis,
                                               const int* __restrict__ bsum) {
    int tid = threadIdx.x;
    int g = blockIdx.x * 256 + tid;
    int o = off[g] + bsum[blockIdx.x];
    off[g] = o;
    cursor[g] = o;
    dis[g] = rsqrtf((float)deg[g]);
    if (g == 0) off[N_NODES] = E_TOT;
}

// XCD-sliced counting-sort scatter: block b handles dst slice (b&7); 256 chunks
// per slice (2048 blocks total) so the slice re-read is parallel. src is only
// read for in-slice edges.
__global__ void k_scatter(const int* __restrict__ src, const int* __restrict__ dst,
                          int* __restrict__ cursor, int* __restrict__ ssort) {
    int g   = blockIdx.x & 7;
    int blk = blockIdx.x >> 3;
    int lo = g * NSLICE, hi = lo + NSLICE;
    int e0 = blk * SCHUNK;
    int e1 = e0 + SCHUNK; if (e1 > E_TOT) e1 = E_TOT;
    for (int e = e0 + threadIdx.x; e < e1; e += 256) {
        int d = (e < N_EDGES) ? dst[e] : (e - N_EDGES);
        if (d >= lo && d < hi) {
            int s = (e < N_EDGES) ? src[e] : d;
            int pos = atomicAdd(&cursor[d], 1);
            ssort[pos] = s;
        }
    }
}

// ---------------- W -> fragment-ordered bf16 hi/lo ----------------

__global__ void k_convw(const float* __restrict__ W, int K, int N,
                        short* __restrict__ Bh, short* __restrict__ Bl) {
    int g = blockIdx.x * 256 + threadIdx.x;
    int total = (N / 16) * (K / 32) * 64;
    if (g >= total) return;
    int lane = g & 63;
    int kt = (g >> 6) % (K / 32);
    int nt = (g >> 6) / (K / 32);
    int n = nt * 16 + (lane & 15);
    int kbase = kt * 32 + (lane >> 4) * 8;
    #pragma unroll
    for (int j = 0; j < 8; ++j) {
        short h, l;
        split_bf16(W[(size_t)(kbase + j) * N + n], h, l);
        Bh[(size_t)g * 8 + j] = h;
        Bl[(size_t)g * 8 + j] = l;
    }
}

// ---------------- split-bf16 MFMA GEMM: C[M,N] = A[M,K] @ W ----------------

template <int K, int N, bool ACT, bool SCALE_OUT>
__global__ __launch_bounds__(256) void k_mm(const float* __restrict__ A,
                                            const short* __restrict__ Bh, const short* __restrict__ Bl,
                                            const float* __restrict__ bias, const float* __restrict__ dis,
                                            float* __restrict__ C) {
    constexpr int NT = N / 16;
    constexpr int KT = K / 32;
    __shared__ short Ah[4 * 64 * 8];
    __shared__ short Al[4 * 64 * 8];
    int tid = threadIdx.x;
    int wave = tid >> 6, lane = tid & 63;
    int quad = lane >> 4, col = lane & 15;
    size_t row0 = (size_t)blockIdx.x * 64;

    floatx4 acc[NT];
    #pragma unroll
    for (int t = 0; t < NT; ++t) acc[t] = (floatx4)0.0f;

    int srow = tid >> 2;
    int sdst = ((srow >> 4) * 64 + (srow & 15) + ((tid & 3) << 4)) * 8;
    const float* arow = A + (row0 + srow) * K + (tid & 3) * 8;

    for (int kt = 0; kt < KT; ++kt) {
        float4 a0 = *(const float4*)(arow + kt * 32);
        float4 a1 = *(const float4*)(arow + kt * 32 + 4);
        float av[8] = {a0.x, a0.y, a0.z, a0.w, a1.x, a1.y, a1.z, a1.w};
        short h[8], l[8];
        #pragma unroll
        for (int j = 0; j < 8; ++j) split_bf16(av[j], h[j], l[j]);
        __syncthreads();
        *(short8*)(&Ah[sdst]) = *(short8*)h;
        *(short8*)(&Al[sdst]) = *(short8*)l;
        __syncthreads();
        short8 afh = *(short8*)(&Ah[(wave * 64 + lane) * 8]);
        short8 afl = *(short8*)(&Al[(wave * 64 + lane) * 8]);
        #pragma unroll
        for (int nt = 0; nt < NT; ++nt) {
            size_t bi = ((size_t)(nt * KT + kt) * 64 + lane);
            short8 bfh = ((const short8*)Bh)[bi];
            short8 bfl = ((const short8*)Bl)[bi];
            acc[nt] = __builtin_amdgcn_mfma_f32_16x16x32_bf16(afh, bfh, acc[nt], 0, 0, 0);
            acc[nt] = __builtin_amdgcn_mfma_f32_16x16x32_bf16(afh, bfl, acc[nt], 0, 0, 0);
            acc[nt] = __builtin_amdgcn_mfma_f32_16x16x32_bf16(afl, bfh, acc[nt], 0, 0, 0);
        }
    }

    size_t rbase = row0 + wave * 16 + quad * 4;
    if (!ACT) {
        float4 d4 = make_float4(1.f, 1.f, 1.f, 1.f);
        if (SCALE_OUT) d4 = *(const float4*)(dis + rbase);
        float dr[4] = {d4.x, d4.y, d4.z, d4.w};
        #pragma unroll
        for (int nt = 0; nt < NT; ++nt)
            #pragma unroll
            for (int r = 0; r < 4; ++r)
                C[(rbase + r) * N + nt * 16 + col] = acc[nt][r] * dr[r];
    } else {
        float bv[NT];
        #pragma unroll
        for (int nt = 0; nt < NT; ++nt) bv[nt] = bias[nt * 16 + col];
        float mr[4] = {0.f, 0.f, 0.f, 0.f};
        #pragma unroll
        for (int nt = 0; nt < NT; ++nt)
            #pragma unroll
            for (int r = 0; r < 4; ++r) {
                float v = fmaxf(acc[nt][r] + bv[nt], 0.0f);
                acc[nt][r] = v;
                mr[r] = fmaxf(mr[r], v);
            }
        #pragma unroll
        for (int mask = 1; mask < 16; mask <<= 1)
            #pragma unroll
            for (int r = 0; r < 4; ++r) mr[r] = fmaxf(mr[r], __shfl_xor(mr[r], mask, 64));
        float sr[4] = {0.f, 0.f, 0.f, 0.f};
        #pragma unroll
        for (int nt = 0; nt < NT; ++nt)
            #pragma unroll
            for (int r = 0; r < 4; ++r) {
                float t = __expf(acc[nt][r] - mr[r]);
                acc[nt][r] = t;
                sr[r] += t;
            }
        #pragma unroll
        for (int mask = 1; mask < 16; mask <<= 1)
            #pragma unroll
            for (int r = 0; r < 4; ++r) sr[r] += __shfl_xor(sr[r], mask, 64);
        float inv[4];
        #pragma unroll
        for (int r = 0; r < 4; ++r) inv[r] = 1.0f / sr[r];
        #pragma unroll
        for (int nt = 0; nt < NT; ++nt)
            #pragma unroll
            for (int r = 0; r < 4; ++r)
                C[(rbase + r) * N + nt * 16 + col] = acc[nt][r] * inv[r];
    }
}

// ---------------- aggregation, DOUT=128: half-wave x float4 per edge, 8 gathers in flight ----------------

template <bool SCALE_SRC, bool ACT>
__global__ __launch_bounds__(256) void k_agg128(const float* __restrict__ h, const int* __restrict__ off,
                                                const int* __restrict__ ss, const float* __restrict__ dis,
                                                const float* __restrict__ bias, float* __restrict__ out) {
    int lane = threadIdx.x & 63;
    int half = lane >> 5;
    int li = lane & 31;
    int c0 = 4 * li;
    int n = blockIdx.x * 4 + (threadIdx.x >> 6);
    int e0 = off[n], e1 = off[n + 1];
    int e = e0;
    float4 acc = make_float4(0.f, 0.f, 0.f, 0.f);

    // 16 edges per iter -> 8 outstanding dwordx4 gathers per lane
    for (; e + 16 <= e1; e += 16) {
        int s0 = ss[e + 0 + half];
        int s1 = ss[e + 2 + half];
        int s2 = ss[e + 4 + half];
        int s3 = ss[e + 6 + half];
        int s4 = ss[e + 8 + half];
        int s5 = ss[e + 10 + half];
        int s6 = ss[e + 12 + half];
        int s7 = ss[e + 14 + half];
        float4 v0 = *(const float4*)(h + (size_t)s0 * 128 + c0);
        float4 v1 = *(const float4*)(h + (size_t)s1 * 128 + c0);
        float4 v2 = *(const float4*)(h + (size_t)s2 * 128 + c0);
        float4 v3 = *(const float4*)(h + (size_t)s3 * 128 + c0);
        float4 v4 = *(const float4*)(h + (size_t)s4 * 128 + c0);
        float4 v5 = *(const float4*)(h + (size_t)s5 * 128 + c0);
        float4 v6 = *(const float4*)(h + (size_t)s6 * 128 + c0);
        float4 v7 = *(const float4*)(h + (size_t)s7 * 128 + c0);
        float w0 = SCALE_SRC ? dis[s0] : 1.0f;
        float w1 = SCALE_SRC ? dis[s1] : 1.0f;
        float w2 = SCALE_SRC ? dis[s2] : 1.0f;
        float w3 = SCALE_SRC ? dis[s3] : 1.0f;
        float w4 = SCALE_SRC ? dis[s4] : 1.0f;
        float w5 = SCALE_SRC ? dis[s5] : 1.0f;
        float w6 = SCALE_SRC ? dis[s6] : 1.0f;
        float w7 = SCALE_SRC ? dis[s7] : 1.0f;
        acc.x = fmaf(w0, v0.x, acc.x); acc.y = fmaf(w0, v0.y, acc.y);
        acc.z = fmaf(w0, v0.z, acc.z); acc.w = fmaf(w0, v0.w, acc.w);
        acc.x = fmaf(w1, v1.x, acc.x); acc.y = fmaf(w1, v1.y, acc.y);
        acc.z = fmaf(w1, v1.z, acc.z); acc.w = fmaf(w1, v1.w, acc.w);
        acc.x = fmaf(w2, v2.x, acc.x); acc.y = fmaf(w2, v2.y, acc.y);
        acc.z = fmaf(w2, v2.z, acc.z); acc.w = fmaf(w2, v2.w, acc.w);
        acc.x = fmaf(w3, v3.x, acc.x); acc.y = fmaf(w3, v3.y, acc.y);
        acc.z = fmaf(w3, v3.z, acc.z); acc.w = fmaf(w3, v3.w, acc.w);
        acc.x = fmaf(w4, v4.x, acc.x); acc.y = fmaf(w4, v4.y, acc.y);
        acc.z = fmaf(w4, v4.z, acc.z); acc.w = fmaf(w4, v4.w, acc.w);
        acc.x = fmaf(w5, v5.x, acc.x); acc.y = fmaf(w5, v5.y, acc.y);
        acc.z = fmaf(w5, v5.z, acc.z); acc.w = fmaf(w5, v5.w, acc.w);
        acc.x = fmaf(w6, v6.x, acc.x); acc.y = fmaf(w6, v6.y, acc.y);
        acc.z = fmaf(w6, v6.z, acc.z); acc.w = fmaf(w6, v6.w, acc.w);
        acc.x = fmaf(w7, v7.x, acc.x); acc.y = fmaf(w7, v7.y, acc.y);
        acc.z = fmaf(w7, v7.z, acc.z); acc.w = fmaf(w7, v7.w, acc.w);
    }
    for (; e + 2 <= e1; e += 2) {
        int s = ss[e + half];
        float4 v = *(const float4*)(h + (size_t)s * 128 + c0);
        float w = SCALE_SRC ? dis[s] : 1.0f;
        acc.x = fmaf(w, v.x, acc.x); acc.y = fmaf(w, v.y, acc.y);
        acc.z = fmaf(w, v.z, acc.z); acc.w = fmaf(w, v.w, acc.w);
    }
    if (e < e1) {  // odd tail: only half 0 contributes
        int s = ss[e];
        float4 v = *(const float4*)(h + (size_t)s * 128 + c0);
        float w = (half == 0) ? (SCALE_SRC ? dis[s] : 1.0f) : 0.0f;
        acc.x = fmaf(w, v.x, acc.x); acc.y = fmaf(w, v.y, acc.y);
        acc.z = fmaf(w, v.z, acc.z); acc.w = fmaf(w, v.w, acc.w);
    }

    acc.x += __shfl_xor(acc.x, 32, 64);
    acc.y += __shfl_xor(acc.y, 32, 64);
    acc.z += __shfl_xor(acc.z, 32, 64);
    acc.w += __shfl_xor(acc.w, 32, 64);

    float dn = dis[n];
    acc.x *= dn; acc.y *= dn; acc.z *= dn; acc.w *= dn;

    if (ACT) {
        float4 b4 = *(const float4*)(bias + c0);
        float v[4] = {fmaxf(acc.x + b4.x, 0.f), fmaxf(acc.y + b4.y, 0.f),
                      fmaxf(acc.z + b4.z, 0.f), fmaxf(acc.w + b4.w, 0.f)};
        float m = fmaxf(fmaxf(v[0], v[1]), fmaxf(v[2], v[3]));
        #pragma unroll
        for (int mask = 16; mask > 0; mask >>= 1) m = fmaxf(m, __shfl_xor(m, mask, 64));
        float sum = 0.f;
        #pragma unroll
        for (int j = 0; j < 4; ++j) {
            v[j] = __expf(v[j] - m);
            sum += v[j];
        }
        #pragma unroll
        for (int mask = 16; mask > 0; mask >>= 1) sum += __shfl_xor(sum, mask, 64);
        float inv = 1.0f / sum;
        if (half == 0)
            *(float4*)(out + (size_t)n * 128 + c0) = make_float4(v[0] * inv, v[1] * inv, v[2] * inv, v[3] * inv);
    } else {
        if (half == 0)
            *(float4*)(out + (size_t)n * 128 + c0) = acc;
    }
}

// ---------------- aggregation, DOUT=64: quarter-wave x float4 per edge ----------------

__global__ __launch_bounds__(256) void k_agg64(const float* __restrict__ h, const int* __restrict__ off,
                                               const int* __restrict__ ss, const float* __restrict__ dis,
                                               const float* __restrict__ bias, float* __restrict__ out) {
    int lane = threadIdx.x & 63;
    int sub = lane >> 4;
    int li = lane & 15;
    int c0 = 4 * li;
    int n = blockIdx.x * 4 + (threadIdx.x >> 6);
    int e0 = off[n], e1 = off[n + 1];
    int e = e0;
    float4 acc = make_float4(0.f, 0.f, 0.f, 0.f);

    for (; e + 16 <= e1; e += 16) {
        int s0 = ss[e + sub];
        int s1 = ss[e + 4 + sub];
        int s2 = ss[e + 8 + sub];
        int s3 = ss[e + 12 + sub];
        float4 v0 = *(const float4*)(h + (size_t)s0 * 64 + c0);
        float4 v1 = *(const float4*)(h + (size_t)s1 * 64 + c0);
        float4 v2 = *(const float4*)(h + (size_t)s2 * 64 + c0);
        float4 v3 = *(const float4*)(h + (size_t)s3 * 64 + c0);
        acc.x += v0.x + v1.x + v2.x + v3.x;
        acc.y += v0.y + v1.y + v2.y + v3.y;
        acc.z += v0.z + v1.z + v2.z + v3.z;
        acc.w += v0.w + v1.w + v2.w + v3.w;
    }
    for (; e + 4 <= e1; e += 4) {
        int s = ss[e + sub];
        float4 v = *(const float4*)(h + (size_t)s * 64 + c0);
        acc.x += v.x; acc.y += v.y; acc.z += v.z; acc.w += v.w;
    }
    int rem = e1 - e;
    if (rem > 0) {
        int idx = e + sub;
        if (idx >= e1) idx = e1 - 1;
        int s = ss[idx];
        float4 v = *(const float4*)(h + (size_t)s * 64 + c0);
        float w = (sub < rem) ? 1.0f : 0.0f;
        acc.x = fmaf(w, v.x, acc.x); acc.y = fmaf(w, v.y, acc.y);
        acc.z = fmaf(w, v.z, acc.z); acc.w = fmaf(w, v.w, acc.w);
    }

    #pragma unroll
    for (int mask = 32; mask >= 16; mask >>= 1) {
        acc.x += __shfl_xor(acc.x, mask, 64);
        acc.y += __shfl_xor(acc.y, mask, 64);
        acc.z += __shfl_xor(acc.z, mask, 64);
        acc.w += __shfl_xor(acc.w, mask, 64);
    }

    float dn = dis[n];
    float4 b4 = *(const float4*)(bias + c0);
    float v[4] = {fmaxf(fmaf(acc.x, dn, b4.x), 0.f), fmaxf(fmaf(acc.y, dn, b4.y), 0.f),
                  fmaxf(fmaf(acc.z, dn, b4.z), 0.f), fmaxf(fmaf(acc.w, dn, b4.w), 0.f)};
    float m = fmaxf(fmaxf(v[0], v[1]), fmaxf(v[2], v[3]));
    #pragma unroll
    for (int mask = 8; mask > 0; mask >>= 1) m = fmaxf(m, __shfl_xor(m, mask, 64));
    float sum = 0.f;
    #pragma unroll
    for (int j = 0; j < 4; ++j) {
        v[j] = __expf(v[j] - m);
        sum += v[j];
    }
    #pragma unroll
    for (int mask = 8; mask > 0; mask >>= 1) sum += __shfl_xor(sum, mask, 64);
    float inv = 1.0f / sum;
    if (sub == 0)
        *(float4*)(out + (size_t)n * 64 + c0) = make_float4(v[0] * inv, v[1] * inv, v[2] * inv, v[3] * inv);
}

// ---------------- launch ----------------

extern "C" void kernel_launch(void* const* d_in, const int* in_sizes, int n_in,
                              void* d_out, int out_size, void* d_ws, size_t ws_size,
                              hipStream_t stream) {
    const float* x  = (const float*)d_in[0];
    const int*   ei = (const int*)d_in[1];
    const float* W1 = (const float*)d_in[2];
    const float* b1 = (const float*)d_in[3];
    const float* W2 = (const float*)d_in[4];
    const float* b2 = (const float*)d_in[5];
    const float* W3 = (const float*)d_in[6];
    const float* b3 = (const float*)d_in[7];
    const int* srcE = ei;
    const int* dstE = ei + N_EDGES;

    char* p = (char*)d_ws;
    auto carve = [&](size_t bytes) {
        char* q = p;
        p += (bytes + 255) & ~(size_t)255;
        return q;
    };
    int*   deg   = (int*)carve(sizeof(int) * N_NODES);
    int*   off   = (int*)carve(sizeof(int) * (N_NODES + 1));
    int*   cur   = (int*)carve(sizeof(int) * N_NODES);
    float* dis   = (float*)carve(sizeof(float) * N_NODES);
    int*   bsum  = (int*)carve(sizeof(int) * 256);
    int*   ssort = (int*)carve(sizeof(int) * E_TOT);
    short* w1h   = (short*)carve(sizeof(short) * 128 * 256);
    short* w1l   = (short*)carve(sizeof(short) * 128 * 256);
    short* w2h   = (short*)carve(sizeof(short) * 256 * 128);
    short* w2l   = (short*)carve(sizeof(short) * 256 * 128);
    short* w3h   = (short*)carve(sizeof(short) * 128 * 64);
    short* w3l   = (short*)carve(sizeof(short) * 128 * 64);
    float* bufA  = (float*)carve(sizeof(float) * (size_t)N_NODES * 256);
    float* bufB  = (float*)carve(sizeof(float) * (size_t)N_NODES * 256);

    k_init_deg<<<N_NODES / 256, 256, 0, stream>>>(deg);
    k_hist<<<(N_EDGES + 255) / 256, 256, 0, stream>>>(dstE, deg);
    k_scan1<<<N_NODES / 256, 256, 0, stream>>>(deg, off, bsum);
    k_scan2<<<1, 256, 0, stream>>>(bsum);
    k_scan3<<<N_NODES / 256, 256, 0, stream>>>(deg, off, cur, dis, bsum);
    k_scatter<<<2048, 256, 0, stream>>>(srcE, dstE, cur, ssort);
    k_convw<<<(16 * 4 * 64 + 255) / 256, 256, 0, stream>>>(W1, 128, 256, w1h, w1l);
    k_convw<<<(8 * 8 * 64 + 255) / 256, 256, 0, stream>>>(W2, 256, 128, w2h, w2l);
    k_convw<<<(4 * 4 * 64 + 255) / 256, 256, 0, stream>>>(W3, 128, 64, w3h, w3l);

    // layer 1 (agg-first): a0[n] = dis[n] * sum dis[s]*x[s]; x1 = softmax(relu(a0@W1 + b1))
    k_agg128<true, false><<<N_NODES / 4, 256, 0, stream>>>(x, off, ssort, dis, nullptr, bufB);
    k_mm<128, 256, true, false><<<N_NODES / 64, 256, 0, stream>>>(bufB, w1h, w1l, b1, nullptr, bufA);
    // layer 2: h2' = dis .* (x1@W2); x2 = softmax(relu(dis[n]*segsum(h2') + b2))
    k_mm<256, 128, false, true><<<N_NODES / 64, 256, 0, stream>>>(bufA, w2h, w2l, nullptr, dis, bufB);
    k_agg128<false, true><<<N_NODES / 4, 256, 0, stream>>>(bufB, off, ssort, dis, b2, bufA);
    // layer 3: h3' = dis .* (x2@W3); out = softmax(relu(dis[n]*segsum(h3') + b3))
    k_mm<128, 64, false, true><<<N_NODES / 64, 256, 0, stream>>>(bufA, w3h, w3l, nullptr, dis, bufB);
    k_agg64<<<N_NODES / 4, 256, 0, stream>>>(bufB, off, ssort, dis, b3, (float*)d_out);
}

// Round 7
// 414.263 us; speedup vs baseline: 1.3356x; 1.1670x over previous
//
#include <hip/hip_runtime.h>
#include <cstdint>
#include <cstddef>

#define N_NODES 65536
#define N_EDGES 1048576
#define E_TOT   (N_EDGES + N_NODES)
#define NSLICE  8192                    // N_NODES / 8 XCD slices
#define SCHUNK  ((E_TOT + 255) / 256)   // 4352: 256 chunks per slice

using short8  = __attribute__((ext_vector_type(8))) short;
using floatx4 = __attribute__((ext_vector_type(4))) float;
using half8   = __attribute__((ext_vector_type(8))) _Float16;
using half4   = __attribute__((ext_vector_type(4))) _Float16;

// split fp32 -> bf16 hi (RTN) + bf16 lo (trunc of residual)
__device__ inline void split_bf16(float a, short& hi, short& lo) {
    unsigned u  = __float_as_uint(a);
    unsigned hr = (u + 0x7fffu + ((u >> 16) & 1u)) >> 16;
    float    hf = __uint_as_float(hr << 16);
    hi = (short)hr;
    float    lf = a - hf;
    lo = (short)(__float_as_uint(lf) >> 16);
}

// ---------------- preprocessing ----------------

__global__ void k_init_deg(int* __restrict__ deg) {
    int n = blockIdx.x * 256 + threadIdx.x;
    deg[n] = 1;  // self loop
}

__global__ void k_hist(const int* __restrict__ dst, int* __restrict__ deg) {
    int e = blockIdx.x * 256 + threadIdx.x;
    if (e < N_EDGES) atomicAdd(&deg[dst[e]], 1);
}

__global__ __launch_bounds__(256) void k_scan1(const int* __restrict__ deg, int* __restrict__ off,
                                               int* __restrict__ bsum) {
    __shared__ int sb[256];
    int tid = threadIdx.x;
    int g = blockIdx.x * 256 + tid;
    int v = deg[g];
    sb[tid] = v;
    __syncthreads();
    #pragma unroll
    for (int s = 1; s < 256; s <<= 1) {
        int t = (tid >= s) ? sb[tid - s] : 0;
        __syncthreads();
        sb[tid] += t;
        __syncthreads();
    }
    off[g] = sb[tid] - v;
    if (tid == 255) bsum[blockIdx.x] = sb[255];
}

__global__ __launch_bounds__(256) void k_scan2(int* __restrict__ bsum) {
    __shared__ int sb[256];
    int tid = threadIdx.x;
    int v = bsum[tid];
    sb[tid] = v;
    __syncthreads();
    #pragma unroll
    for (int s = 1; s < 256; s <<= 1) {
        int t = (tid >= s) ? sb[tid - s] : 0;
        __syncthreads();
        sb[tid] += t;
        __syncthreads();
    }
    bsum[tid] = sb[tid] - v;
}

__global__ __launch_bounds__(256) void k_scan3(const int* __restrict__ deg, int* __restrict__ off,
                                               int* __restrict__ cursor, float* __restrict__ dis,
                                               const int* __restrict__ bsum) {
    int tid = threadIdx.x;
    int g = blockIdx.x * 256 + tid;
    int o = off[g] + bsum[blockIdx.x];
    off[g] = o;
    cursor[g] = o;
    dis[g] = rsqrtf((float)deg[g]);
    if (g == 0) off[N_NODES] = E_TOT;
}

// XCD-sliced counting-sort scatter (round-6 version: 2048 blocks, slice = blockIdx&7)
__global__ void k_scatter(const int* __restrict__ src, const int* __restrict__ dst,
                          int* __restrict__ cursor, int* __restrict__ ssort) {
    int g   = blockIdx.x & 7;
    int blk = blockIdx.x >> 3;
    int lo = g * NSLICE, hi = lo + NSLICE;
    int e0 = blk * SCHUNK;
    int e1 = e0 + SCHUNK; if (e1 > E_TOT) e1 = E_TOT;
    for (int e = e0 + threadIdx.x; e < e1; e += 256) {
        int d = (e < N_EDGES) ? dst[e] : (e - N_EDGES);
        if (d >= lo && d < hi) {
            int s = (e < N_EDGES) ? src[e] : d;
            int pos = atomicAdd(&cursor[d], 1);
            ssort[pos] = s;
        }
    }
}

// ---------------- x -> fp16 rows pre-scaled by dis[row] ----------------

__global__ __launch_bounds__(256) void k_convx(const float* __restrict__ x, const float* __restrict__ dis,
                                               _Float16* __restrict__ xh) {
    int g = blockIdx.x * 256 + threadIdx.x;   // group of 4 elements
    int idx = g * 4;
    int row = idx >> 7;
    float d = dis[row];
    float4 v = *(const float4*)(x + idx);
    half4 o = {(_Float16)(d * v.x), (_Float16)(d * v.y), (_Float16)(d * v.z), (_Float16)(d * v.w)};
    *(half4*)(xh + idx) = o;
}

// ---------------- W -> fragment-ordered bf16 hi/lo ----------------

__global__ void k_convw(const float* __restrict__ W, int K, int N,
                        short* __restrict__ Bh, short* __restrict__ Bl) {
    int g = blockIdx.x * 256 + threadIdx.x;
    int total = (N / 16) * (K / 32) * 64;
    if (g >= total) return;
    int lane = g & 63;
    int kt = (g >> 6) % (K / 32);
    int nt = (g >> 6) / (K / 32);
    int n = nt * 16 + (lane & 15);
    int kbase = kt * 32 + (lane >> 4) * 8;
    #pragma unroll
    for (int j = 0; j < 8; ++j) {
        short h, l;
        split_bf16(W[(size_t)(kbase + j) * N + n], h, l);
        Bh[(size_t)g * 8 + j] = h;
        Bl[(size_t)g * 8 + j] = l;
    }
}

// ---------------- split-bf16 MFMA GEMM: C[M,N] = A[M,K] @ W ----------------
// ACT:  C = softmax(relu(C + bias)), fp32 out.
// else: C = dis[row] * C, written as fp16 rows (consumed only by the gather).

template <int K, int N, bool ACT>
__global__ __launch_bounds__(256) void k_mm(const float* __restrict__ A,
                                            const short* __restrict__ Bh, const short* __restrict__ Bl,
                                            const float* __restrict__ bias, const float* __restrict__ dis,
                                            void* __restrict__ Cout) {
    constexpr int NT = N / 16;
    constexpr int KT = K / 32;
    __shared__ short Ah[4 * 64 * 8];
    __shared__ short Al[4 * 64 * 8];
    int tid = threadIdx.x;
    int wave = tid >> 6, lane = tid & 63;
    int quad = lane >> 4, col = lane & 15;
    size_t row0 = (size_t)blockIdx.x * 64;

    floatx4 acc[NT];
    #pragma unroll
    for (int t = 0; t < NT; ++t) acc[t] = (floatx4)0.0f;

    int srow = tid >> 2;
    int sdst = ((srow >> 4) * 64 + (srow & 15) + ((tid & 3) << 4)) * 8;
    const float* arow = A + (row0 + srow) * K + (tid & 3) * 8;

    for (int kt = 0; kt < KT; ++kt) {
        float4 a0 = *(const float4*)(arow + kt * 32);
        float4 a1 = *(const float4*)(arow + kt * 32 + 4);
        float av[8] = {a0.x, a0.y, a0.z, a0.w, a1.x, a1.y, a1.z, a1.w};
        short h[8], l[8];
        #pragma unroll
        for (int j = 0; j < 8; ++j) split_bf16(av[j], h[j], l[j]);
        __syncthreads();
        *(short8*)(&Ah[sdst]) = *(short8*)h;
        *(short8*)(&Al[sdst]) = *(short8*)l;
        __syncthreads();
        short8 afh = *(short8*)(&Ah[(wave * 64 + lane) * 8]);
        short8 afl = *(short8*)(&Al[(wave * 64 + lane) * 8]);
        #pragma unroll
        for (int nt = 0; nt < NT; ++nt) {
            size_t bi = ((size_t)(nt * KT + kt) * 64 + lane);
            short8 bfh = ((const short8*)Bh)[bi];
            short8 bfl = ((const short8*)Bl)[bi];
            acc[nt] = __builtin_amdgcn_mfma_f32_16x16x32_bf16(afh, bfh, acc[nt], 0, 0, 0);
            acc[nt] = __builtin_amdgcn_mfma_f32_16x16x32_bf16(afh, bfl, acc[nt], 0, 0, 0);
            acc[nt] = __builtin_amdgcn_mfma_f32_16x16x32_bf16(afl, bfh, acc[nt], 0, 0, 0);
        }
    }

    size_t rbase = row0 + wave * 16 + quad * 4;
    if (!ACT) {
        _Float16* Ch = (_Float16*)Cout;
        float4 d4 = *(const float4*)(dis + rbase);
        float dr[4] = {d4.x, d4.y, d4.z, d4.w};
        #pragma unroll
        for (int nt = 0; nt < NT; ++nt)
            #pragma unroll
            for (int r = 0; r < 4; ++r)
                Ch[(rbase + r) * N + nt * 16 + col] = (_Float16)(acc[nt][r] * dr[r]);
    } else {
        float* C = (float*)Cout;
        float bv[NT];
        #pragma unroll
        for (int nt = 0; nt < NT; ++nt) bv[nt] = bias[nt * 16 + col];
        float mr[4] = {0.f, 0.f, 0.f, 0.f};
        #pragma unroll
        for (int nt = 0; nt < NT; ++nt)
            #pragma unroll
            for (int r = 0; r < 4; ++r) {
                float v = fmaxf(acc[nt][r] + bv[nt], 0.0f);
                acc[nt][r] = v;
                mr[r] = fmaxf(mr[r], v);
            }
        #pragma unroll
        for (int mask = 1; mask < 16; mask <<= 1)
            #pragma unroll
            for (int r = 0; r < 4; ++r) mr[r] = fmaxf(mr[r], __shfl_xor(mr[r], mask, 64));
        float sr[4] = {0.f, 0.f, 0.f, 0.f};
        #pragma unroll
        for (int nt = 0; nt < NT; ++nt)
            #pragma unroll
            for (int r = 0; r < 4; ++r) {
                float t = __expf(acc[nt][r] - mr[r]);
                acc[nt][r] = t;
                sr[r] += t;
            }
        #pragma unroll
        for (int mask = 1; mask < 16; mask <<= 1)
            #pragma unroll
            for (int r = 0; r < 4; ++r) sr[r] += __shfl_xor(sr[r], mask, 64);
        float inv[4];
        #pragma unroll
        for (int r = 0; r < 4; ++r) inv[r] = 1.0f / sr[r];
        #pragma unroll
        for (int nt = 0; nt < NT; ++nt)
            #pragma unroll
            for (int r = 0; r < 4; ++r)
                C[(rbase + r) * N + nt * 16 + col] = acc[nt][r] * inv[r];
    }
}

// ---------------- aggregation, DOUT=128, fp16 rows: quarter-wave (16 lanes x 16B) per edge ----------------
// rows pre-scaled by dis[src]. out = dis[n]*sum (ACT: +bias, relu, softmax), fp32 out.

template <bool ACT>
__global__ __launch_bounds__(256) void k_agg128h(const _Float16* __restrict__ h, const int* __restrict__ off,
                                                 const int* __restrict__ ss, const float* __restrict__ dis,
                                                 const float* __restrict__ bias, float* __restrict__ out) {
    int lane = threadIdx.x & 63;
    int sub = lane >> 4;      // 0..3: edge slot
    int li  = lane & 15;      // column group: halfs [li*8, li*8+8)
    int c0  = li * 8;
    int n = blockIdx.x * 4 + (threadIdx.x >> 6);
    int e0 = off[n], e1 = off[n + 1];
    int e = e0;
    float acc[8];
    #pragma unroll
    for (int j = 0; j < 8; ++j) acc[j] = 0.0f;

    // 8 edges per iter: 2 gathers per lane, quarter-wave per edge
    for (; e + 8 <= e1; e += 8) {
        int sa = ss[e + sub];
        int sb = ss[e + 4 + sub];
        half8 va = *(const half8*)(h + (size_t)sa * 128 + c0);
        half8 vb = *(const half8*)(h + (size_t)sb * 128 + c0);
        #pragma unroll
        for (int j = 0; j < 8; ++j) acc[j] += (float)va[j] + (float)vb[j];
    }
    // masked remainder, 4 at a time
    while (e < e1) {
        int rem = e1 - e;
        int idx = e + sub;
        if (idx >= e1) idx = e1 - 1;
        int s = ss[idx];
        half8 v = *(const half8*)(h + (size_t)s * 128 + c0);
        float w = (sub < rem) ? 1.0f : 0.0f;
        #pragma unroll
        for (int j = 0; j < 8; ++j) acc[j] = fmaf(w, (float)v[j], acc[j]);
        e += 4;
    }

    // combine the 4 edge slots
    #pragma unroll
    for (int mask = 32; mask >= 16; mask >>= 1)
        #pragma unroll
        for (int j = 0; j < 8; ++j) acc[j] += __shfl_xor(acc[j], mask, 64);

    float dn = dis[n];
    if (ACT) {
        float m = 0.0f;
        #pragma unroll
        for (int j = 0; j < 8; ++j) {
            float v = fmaxf(fmaf(acc[j], dn, bias[c0 + j]), 0.0f);
            acc[j] = v;
            m = fmaxf(m, v);
        }
        #pragma unroll
        for (int mask = 8; mask > 0; mask >>= 1) m = fmaxf(m, __shfl_xor(m, mask, 64));
        float sum = 0.0f;
        #pragma unroll
        for (int j = 0; j < 8; ++j) {
            float t = __expf(acc[j] - m);
            acc[j] = t;
            sum += t;
        }
        #pragma unroll
        for (int mask = 8; mask > 0; mask >>= 1) sum += __shfl_xor(sum, mask, 64);
        float inv = 1.0f / sum;
        #pragma unroll
        for (int j = 0; j < 8; ++j) acc[j] *= inv;
    } else {
        #pragma unroll
        for (int j = 0; j < 8; ++j) acc[j] *= dn;
    }
    if (sub == 0) {
        float* op = out + (size_t)n * 128 + c0;
        *(float4*)(op)     = make_float4(acc[0], acc[1], acc[2], acc[3]);
        *(float4*)(op + 4) = make_float4(acc[4], acc[5], acc[6], acc[7]);
    }
}

// ---------------- aggregation, DOUT=64, fp16 rows: eighth-wave (8 lanes x 16B) per edge ----------------

__global__ __launch_bounds__(256) void k_agg64h(const _Float16* __restrict__ h, const int* __restrict__ off,
                                                const int* __restrict__ ss, const float* __restrict__ dis,
                                                const float* __restrict__ bias, float* __restrict__ out) {
    int lane = threadIdx.x & 63;
    int sub = lane >> 3;      // 0..7: edge slot
    int li  = lane & 7;       // column group: halfs [li*8, li*8+8)
    int c0  = li * 8;
    int n = blockIdx.x * 4 + (threadIdx.x >> 6);
    int e0 = off[n], e1 = off[n + 1];
    int e = e0;
    float acc[8];
    #pragma unroll
    for (int j = 0; j < 8; ++j) acc[j] = 0.0f;

    // 8 edges per iter: 1 gather per lane
    for (; e + 8 <= e1; e += 8) {
        int s = ss[e + sub];
        half8 v = *(const half8*)(h + (size_t)s * 64 + c0);
        #pragma unroll
        for (int j = 0; j < 8; ++j) acc[j] += (float)v[j];
    }
    int rem = e1 - e;
    if (rem > 0) {
        int idx = e + sub;
        if (idx >= e1) idx = e1 - 1;
        int s = ss[idx];
        half8 v = *(const half8*)(h + (size_t)s * 64 + c0);
        float w = (sub < rem) ? 1.0f : 0.0f;
        #pragma unroll
        for (int j = 0; j < 8; ++j) acc[j] = fmaf(w, (float)v[j], acc[j]);
    }

    // combine the 8 edge slots
    #pragma unroll
    for (int mask = 32; mask >= 8; mask >>= 1)
        #pragma unroll
        for (int j = 0; j < 8; ++j) acc[j] += __shfl_xor(acc[j], mask, 64);

    float dn = dis[n];
    float m = 0.0f;
    #pragma unroll
    for (int j = 0; j < 8; ++j) {
        float v = fmaxf(fmaf(acc[j], dn, bias[c0 + j]), 0.0f);
        acc[j] = v;
        m = fmaxf(m, v);
    }
    #pragma unroll
    for (int mask = 4; mask > 0; mask >>= 1) m = fmaxf(m, __shfl_xor(m, mask, 64));
    float sum = 0.0f;
    #pragma unroll
    for (int j = 0; j < 8; ++j) {
        float t = __expf(acc[j] - m);
        acc[j] = t;
        sum += t;
    }
    #pragma unroll
    for (int mask = 4; mask > 0; mask >>= 1) sum += __shfl_xor(sum, mask, 64);
    float inv = 1.0f / sum;
    if (sub == 0) {
        float* op = out + (size_t)n * 64 + c0;
        *(float4*)(op)     = make_float4(acc[0] * inv, acc[1] * inv, acc[2] * inv, acc[3] * inv);
        *(float4*)(op + 4) = make_float4(acc[4] * inv, acc[5] * inv, acc[6] * inv, acc[7] * inv);
    }
}

// ---------------- launch ----------------

extern "C" void kernel_launch(void* const* d_in, const int* in_sizes, int n_in,
                              void* d_out, int out_size, void* d_ws, size_t ws_size,
                              hipStream_t stream) {
    const float* x  = (const float*)d_in[0];
    const int*   ei = (const int*)d_in[1];
    const float* W1 = (const float*)d_in[2];
    const float* b1 = (const float*)d_in[3];
    const float* W2 = (const float*)d_in[4];
    const float* b2 = (const float*)d_in[5];
    const float* W3 = (const float*)d_in[6];
    const float* b3 = (const float*)d_in[7];
    const int* srcE = ei;
    const int* dstE = ei + N_EDGES;

    char* p = (char*)d_ws;
    auto carve = [&](size_t bytes) {
        char* q = p;
        p += (bytes + 255) & ~(size_t)255;
        return q;
    };
    int*      deg   = (int*)carve(sizeof(int) * N_NODES);
    int*      off   = (int*)carve(sizeof(int) * (N_NODES + 1));
    int*      cur   = (int*)carve(sizeof(int) * N_NODES);
    float*    dis   = (float*)carve(sizeof(float) * N_NODES);
    int*      bsum  = (int*)carve(sizeof(int) * 256);
    int*      ssort = (int*)carve(sizeof(int) * E_TOT);
    short*    w1h   = (short*)carve(sizeof(short) * 128 * 256);
    short*    w1l   = (short*)carve(sizeof(short) * 128 * 256);
    short*    w2h   = (short*)carve(sizeof(short) * 256 * 128);
    short*    w2l   = (short*)carve(sizeof(short) * 256 * 128);
    short*    w3h   = (short*)carve(sizeof(short) * 128 * 64);
    short*    w3l   = (short*)carve(sizeof(short) * 128 * 64);
    _Float16* xh    = (_Float16*)carve(sizeof(_Float16) * (size_t)N_NODES * 128);
    _Float16* hh    = (_Float16*)carve(sizeof(_Float16) * (size_t)N_NODES * 128);  // h2h then h3h
    float*    bufA  = (float*)carve(sizeof(float) * (size_t)N_NODES * 256);
    float*    bufB  = (float*)carve(sizeof(float) * (size_t)N_NODES * 128);

    k_init_deg<<<N_NODES / 256, 256, 0, stream>>>(deg);
    k_hist<<<(N_EDGES + 255) / 256, 256, 0, stream>>>(dstE, deg);
    k_scan1<<<N_NODES / 256, 256, 0, stream>>>(deg, off, bsum);
    k_scan2<<<1, 256, 0, stream>>>(bsum);
    k_scan3<<<N_NODES / 256, 256, 0, stream>>>(deg, off, cur, dis, bsum);
    k_scatter<<<2048, 256, 0, stream>>>(srcE, dstE, cur, ssort);
    k_convx<<<(N_NODES * 128 / 4) / 256, 256, 0, stream>>>(x, dis, xh);
    k_convw<<<(16 * 4 * 64 + 255) / 256, 256, 0, stream>>>(W1, 128, 256, w1h, w1l);
    k_convw<<<(8 * 8 * 64 + 255) / 256, 256, 0, stream>>>(W2, 256, 128, w2h, w2l);
    k_convw<<<(4 * 4 * 64 + 255) / 256, 256, 0, stream>>>(W3, 128, 64, w3h, w3l);

    // layer 1 (agg-first): a0[n] = dis[n] * sum xh[src]  (xh pre-scaled by dis[src])
    k_agg128h<false><<<N_NODES / 4, 256, 0, stream>>>(xh, off, ssort, dis, nullptr, bufB);
    // x1 = softmax(relu(a0@W1 + b1))  (fp32, GEMM input next layer)
    k_mm<128, 256, true><<<N_NODES / 64, 256, 0, stream>>>(bufB, w1h, w1l, b1, nullptr, bufA);
    // layer 2: h2h = fp16(dis .* (x1@W2)); x2 = softmax(relu(dis[n]*segsum(h2h) + b2))
    k_mm<256, 128, false><<<N_NODES / 64, 256, 0, stream>>>(bufA, w2h, w2l, nullptr, dis, hh);
    k_agg128h<true><<<N_NODES / 4, 256, 0, stream>>>(hh, off, ssort, dis, b2, bufB);
    // layer 3: h3h = fp16(dis .* (x2@W3)); out = softmax(relu(dis[n]*segsum(h3h) + b3))
    k_mm<128, 64, false><<<N_NODES / 64, 256, 0, stream>>>(bufB, w3h, w3l, nullptr, dis, hh);
    k_agg64h<<<N_NODES / 4, 256, 0, stream>>>(hh, off, ssort, dis, b3, (float*)d_out);
}

// Round 8
// 402.815 us; speedup vs baseline: 1.3735x; 1.0284x over previous
//
#include <hip/hip_runtime.h>
#include <cstdint>
#include <cstddef>

#define N_NODES 65536
#define N_EDGES 1048576
#define E_TOT   (N_EDGES + N_NODES)
#define NSLICE  8192                    // N_NODES / 8 XCD slices
#define SCHUNK  ((E_TOT + 255) / 256)   // 4352: 256 chunks per slice

using short8  = __attribute__((ext_vector_type(8))) short;
using floatx4 = __attribute__((ext_vector_type(4))) float;
using half8   = __attribute__((ext_vector_type(8))) _Float16;
using half4   = __attribute__((ext_vector_type(4))) _Float16;
typedef unsigned short ushort_t;

// split fp32 -> bf16 hi (RTN) + bf16 lo (trunc of residual)
__device__ inline void split_bf16(float a, short& hi, short& lo) {
    unsigned u  = __float_as_uint(a);
    unsigned hr = (u + 0x7fffu + ((u >> 16) & 1u)) >> 16;
    float    hf = __uint_as_float(hr << 16);
    hi = (short)hr;
    float    lf = a - hf;
    lo = (short)(__float_as_uint(lf) >> 16);
}

// ---------------- preprocessing ----------------

__global__ void k_init_deg(int* __restrict__ deg) {
    int n = blockIdx.x * 256 + threadIdx.x;
    deg[n] = 1;  // self loop
}

// histogram + pack edges into (src<<16)|dst uint stream
__global__ void k_hist(const int* __restrict__ src, const int* __restrict__ dst,
                       int* __restrict__ deg, unsigned int* __restrict__ ed) {
    int e = blockIdx.x * 256 + threadIdx.x;
    if (e < N_EDGES) {
        int d = dst[e], s = src[e];
        ed[e] = (unsigned int)d | ((unsigned int)s << 16);
        atomicAdd(&deg[d], 1);
    }
}

__global__ __launch_bounds__(256) void k_scan1(const int* __restrict__ deg, int* __restrict__ off,
                                               int* __restrict__ bsum) {
    __shared__ int sb[256];
    int tid = threadIdx.x;
    int g = blockIdx.x * 256 + tid;
    int v = deg[g];
    sb[tid] = v;
    __syncthreads();
    #pragma unroll
    for (int s = 1; s < 256; s <<= 1) {
        int t = (tid >= s) ? sb[tid - s] : 0;
        __syncthreads();
        sb[tid] += t;
        __syncthreads();
    }
    off[g] = sb[tid] - v;
    if (tid == 255) bsum[blockIdx.x] = sb[255];
}

__global__ __launch_bounds__(256) void k_scan2(int* __restrict__ bsum) {
    __shared__ int sb[256];
    int tid = threadIdx.x;
    int v = bsum[tid];
    sb[tid] = v;
    __syncthreads();
    #pragma unroll
    for (int s = 1; s < 256; s <<= 1) {
        int t = (tid >= s) ? sb[tid - s] : 0;
        __syncthreads();
        sb[tid] += t;
        __syncthreads();
    }
    bsum[tid] = sb[tid] - v;
}

__global__ __launch_bounds__(256) void k_scan3(const int* __restrict__ deg, int* __restrict__ off,
                                               int* __restrict__ cursor, float* __restrict__ dis,
                                               const int* __restrict__ bsum) {
    int tid = threadIdx.x;
    int g = blockIdx.x * 256 + tid;
    int o = off[g] + bsum[blockIdx.x];
    off[g] = o;
    cursor[g] = o;
    dis[g] = rsqrtf((float)deg[g]);
    if (g == 0) off[N_NODES] = E_TOT;
}

// XCD-sliced counting-sort scatter: packed edge stream, ushort output
__global__ void k_scatter(const unsigned int* __restrict__ ed,
                          int* __restrict__ cursor, ushort_t* __restrict__ ssort) {
    int g   = blockIdx.x & 7;
    int blk = blockIdx.x >> 3;
    int lo = g * NSLICE, hi = lo + NSLICE;
    int e0 = blk * SCHUNK;
    int e1 = e0 + SCHUNK; if (e1 > E_TOT) e1 = E_TOT;
    for (int e = e0 + threadIdx.x; e < e1; e += 256) {
        int d, s;
        if (e < N_EDGES) { unsigned int v = ed[e]; d = (int)(v & 0xffffu); s = (int)(v >> 16); }
        else             { d = s = e - N_EDGES; }
        if (d >= lo && d < hi) {
            int pos = atomicAdd(&cursor[d], 1);
            ssort[pos] = (ushort_t)s;
        }
    }
}

// ---------------- x -> fp16 rows pre-scaled by dis[row] ----------------

__global__ __launch_bounds__(256) void k_convx(const float* __restrict__ x, const float* __restrict__ dis,
                                               _Float16* __restrict__ xh) {
    int g = blockIdx.x * 256 + threadIdx.x;   // group of 4 elements
    int idx = g * 4;
    int row = idx >> 7;
    float d = dis[row];
    float4 v = *(const float4*)(x + idx);
    half4 o = {(_Float16)(d * v.x), (_Float16)(d * v.y), (_Float16)(d * v.z), (_Float16)(d * v.w)};
    *(half4*)(xh + idx) = o;
}

// ---------------- W -> fragment-ordered bf16 hi/lo ----------------

__global__ void k_convw(const float* __restrict__ W, int K, int N,
                        short* __restrict__ Bh, short* __restrict__ Bl) {
    int g = blockIdx.x * 256 + threadIdx.x;
    int total = (N / 16) * (K / 32) * 64;
    if (g >= total) return;
    int lane = g & 63;
    int kt = (g >> 6) % (K / 32);
    int nt = (g >> 6) / (K / 32);
    int n = nt * 16 + (lane & 15);
    int kbase = kt * 32 + (lane >> 4) * 8;
    #pragma unroll
    for (int j = 0; j < 8; ++j) {
        short h, l;
        split_bf16(W[(size_t)(kbase + j) * N + n], h, l);
        Bh[(size_t)g * 8 + j] = h;
        Bl[(size_t)g * 8 + j] = l;
    }
}

// ---------------- split-bf16 MFMA GEMM: C[M,N] = A[M,K] @ W ----------------
// A is fp16 rows. ACT: C = softmax(relu(C + bias)) -> fp16.
// else: C = dis[row] * C -> fp16 (feeds the gather).

template <int K, int N, bool ACT>
__global__ __launch_bounds__(256) void k_mm(const _Float16* __restrict__ A,
                                            const short* __restrict__ Bh, const short* __restrict__ Bl,
                                            const float* __restrict__ bias, const float* __restrict__ dis,
                                            _Float16* __restrict__ Cout) {
    constexpr int NT = N / 16;
    constexpr int KT = K / 32;
    __shared__ short Ah[4 * 64 * 8];
    __shared__ short Al[4 * 64 * 8];
    int tid = threadIdx.x;
    int wave = tid >> 6, lane = tid & 63;
    int quad = lane >> 4, col = lane & 15;
    size_t row0 = (size_t)blockIdx.x * 64;

    floatx4 acc[NT];
    #pragma unroll
    for (int t = 0; t < NT; ++t) acc[t] = (floatx4)0.0f;

    int srow = tid >> 2;
    int sdst = ((srow >> 4) * 64 + (srow & 15) + ((tid & 3) << 4)) * 8;
    const _Float16* arow = A + (row0 + srow) * K + (tid & 3) * 8;

    for (int kt = 0; kt < KT; ++kt) {
        half8 a8 = *(const half8*)(arow + kt * 32);
        short h[8], l[8];
        #pragma unroll
        for (int j = 0; j < 8; ++j) split_bf16((float)a8[j], h[j], l[j]);
        __syncthreads();
        *(short8*)(&Ah[sdst]) = *(short8*)h;
        *(short8*)(&Al[sdst]) = *(short8*)l;
        __syncthreads();
        short8 afh = *(short8*)(&Ah[(wave * 64 + lane) * 8]);
        short8 afl = *(short8*)(&Al[(wave * 64 + lane) * 8]);
        #pragma unroll
        for (int nt = 0; nt < NT; ++nt) {
            size_t bi = ((size_t)(nt * KT + kt) * 64 + lane);
            short8 bfh = ((const short8*)Bh)[bi];
            short8 bfl = ((const short8*)Bl)[bi];
            acc[nt] = __builtin_amdgcn_mfma_f32_16x16x32_bf16(afh, bfh, acc[nt], 0, 0, 0);
            acc[nt] = __builtin_amdgcn_mfma_f32_16x16x32_bf16(afh, bfl, acc[nt], 0, 0, 0);
            acc[nt] = __builtin_amdgcn_mfma_f32_16x16x32_bf16(afl, bfh, acc[nt], 0, 0, 0);
        }
    }

    size_t rbase = row0 + wave * 16 + quad * 4;
    if (!ACT) {
        float4 d4 = *(const float4*)(dis + rbase);
        float dr[4] = {d4.x, d4.y, d4.z, d4.w};
        #pragma unroll
        for (int nt = 0; nt < NT; ++nt)
            #pragma unroll
            for (int r = 0; r < 4; ++r)
                Cout[(rbase + r) * N + nt * 16 + col] = (_Float16)(acc[nt][r] * dr[r]);
    } else {
        float bv[NT];
        #pragma unroll
        for (int nt = 0; nt < NT; ++nt) bv[nt] = bias[nt * 16 + col];
        float mr[4] = {0.f, 0.f, 0.f, 0.f};
        #pragma unroll
        for (int nt = 0; nt < NT; ++nt)
            #pragma unroll
            for (int r = 0; r < 4; ++r) {
                float v = fmaxf(acc[nt][r] + bv[nt], 0.0f);
                acc[nt][r] = v;
                mr[r] = fmaxf(mr[r], v);
            }
        #pragma unroll
        for (int mask = 1; mask < 16; mask <<= 1)
            #pragma unroll
            for (int r = 0; r < 4; ++r) mr[r] = fmaxf(mr[r], __shfl_xor(mr[r], mask, 64));
        float sr[4] = {0.f, 0.f, 0.f, 0.f};
        #pragma unroll
        for (int nt = 0; nt < NT; ++nt)
            #pragma unroll
            for (int r = 0; r < 4; ++r) {
                float t = __expf(acc[nt][r] - mr[r]);
                acc[nt][r] = t;
                sr[r] += t;
            }
        #pragma unroll
        for (int mask = 1; mask < 16; mask <<= 1)
            #pragma unroll
            for (int r = 0; r < 4; ++r) sr[r] += __shfl_xor(sr[r], mask, 64);
        float inv[4];
        #pragma unroll
        for (int r = 0; r < 4; ++r) inv[r] = 1.0f / sr[r];
        #pragma unroll
        for (int nt = 0; nt < NT; ++nt)
            #pragma unroll
            for (int r = 0; r < 4; ++r)
                Cout[(rbase + r) * N + nt * 16 + col] = (_Float16)(acc[nt][r] * inv[r]);
    }
}

// ---------------- aggregation, DOUT=128, fp16 rows: quarter-wave (16 lanes x 16B) per edge ----------------
// rows pre-scaled by dis[src]. out = dis[n]*sum (ACT: +bias, relu, softmax), fp16 out.

template <bool ACT>
__global__ __launch_bounds__(256) void k_agg128h(const _Float16* __restrict__ h, const int* __restrict__ off,
                                                 const ushort_t* __restrict__ ss, const float* __restrict__ dis,
                                                 const float* __restrict__ bias, _Float16* __restrict__ out) {
    int lane = threadIdx.x & 63;
    int sub = lane >> 4;      // 0..3: edge slot
    int li  = lane & 15;      // column group: halfs [li*8, li*8+8)
    int c0  = li * 8;
    int n = blockIdx.x * 4 + (threadIdx.x >> 6);
    int e0 = off[n], e1 = off[n + 1];
    int e = e0;
    float acc[8];
    #pragma unroll
    for (int j = 0; j < 8; ++j) acc[j] = 0.0f;

    // 8 edges per iter: 2 gathers per lane, quarter-wave per edge
    for (; e + 8 <= e1; e += 8) {
        int sa = ss[e + sub];
        int sb = ss[e + 4 + sub];
        half8 va = *(const half8*)(h + (size_t)sa * 128 + c0);
        half8 vb = *(const half8*)(h + (size_t)sb * 128 + c0);
        #pragma unroll
        for (int j = 0; j < 8; ++j) acc[j] += (float)va[j] + (float)vb[j];
    }
    // masked remainder, 4 at a time
    while (e < e1) {
        int rem = e1 - e;
        int idx = e + sub;
        if (idx >= e1) idx = e1 - 1;
        int s = ss[idx];
        half8 v = *(const half8*)(h + (size_t)s * 128 + c0);
        float w = (sub < rem) ? 1.0f : 0.0f;
        #pragma unroll
        for (int j = 0; j < 8; ++j) acc[j] = fmaf(w, (float)v[j], acc[j]);
        e += 4;
    }

    // combine the 4 edge slots
    #pragma unroll
    for (int mask = 32; mask >= 16; mask >>= 1)
        #pragma unroll
        for (int j = 0; j < 8; ++j) acc[j] += __shfl_xor(acc[j], mask, 64);

    float dn = dis[n];
    if (ACT) {
        float m = 0.0f;
        #pragma unroll
        for (int j = 0; j < 8; ++j) {
            float v = fmaxf(fmaf(acc[j], dn, bias[c0 + j]), 0.0f);
            acc[j] = v;
            m = fmaxf(m, v);
        }
        #pragma unroll
        for (int mask = 8; mask > 0; mask >>= 1) m = fmaxf(m, __shfl_xor(m, mask, 64));
        float sum = 0.0f;
        #pragma unroll
        for (int j = 0; j < 8; ++j) {
            float t = __expf(acc[j] - m);
            acc[j] = t;
            sum += t;
        }
        #pragma unroll
        for (int mask = 8; mask > 0; mask >>= 1) sum += __shfl_xor(sum, mask, 64);
        float inv = 1.0f / sum;
        #pragma unroll
        for (int j = 0; j < 8; ++j) acc[j] *= inv;
    } else {
        #pragma unroll
        for (int j = 0; j < 8; ++j) acc[j] *= dn;
    }
    if (sub == 0) {
        half8 o;
        #pragma unroll
        for (int j = 0; j < 8; ++j) o[j] = (_Float16)acc[j];
        *(half8*)(out + (size_t)n * 128 + c0) = o;
    }
}

// ---------------- aggregation, DOUT=64, fp16 rows: eighth-wave (8 lanes x 16B) per edge ----------------

__global__ __launch_bounds__(256) void k_agg64h(const _Float16* __restrict__ h, const int* __restrict__ off,
                                                const ushort_t* __restrict__ ss, const float* __restrict__ dis,
                                                const float* __restrict__ bias, float* __restrict__ out) {
    int lane = threadIdx.x & 63;
    int sub = lane >> 3;      // 0..7: edge slot
    int li  = lane & 7;       // column group: halfs [li*8, li*8+8)
    int c0  = li * 8;
    int n = blockIdx.x * 4 + (threadIdx.x >> 6);
    int e0 = off[n], e1 = off[n + 1];
    int e = e0;
    float acc[8];
    #pragma unroll
    for (int j = 0; j < 8; ++j) acc[j] = 0.0f;

    for (; e + 8 <= e1; e += 8) {
        int s = ss[e + sub];
        half8 v = *(const half8*)(h + (size_t)s * 64 + c0);
        #pragma unroll
        for (int j = 0; j < 8; ++j) acc[j] += (float)v[j];
    }
    int rem = e1 - e;
    if (rem > 0) {
        int idx = e + sub;
        if (idx >= e1) idx = e1 - 1;
        int s = ss[idx];
        half8 v = *(const half8*)(h + (size_t)s * 64 + c0);
        float w = (sub < rem) ? 1.0f : 0.0f;
        #pragma unroll
        for (int j = 0; j < 8; ++j) acc[j] = fmaf(w, (float)v[j], acc[j]);
    }

    #pragma unroll
    for (int mask = 32; mask >= 8; mask >>= 1)
        #pragma unroll
        for (int j = 0; j < 8; ++j) acc[j] += __shfl_xor(acc[j], mask, 64);

    float dn = dis[n];
    float m = 0.0f;
    #pragma unroll
    for (int j = 0; j < 8; ++j) {
        float v = fmaxf(fmaf(acc[j], dn, bias[c0 + j]), 0.0f);
        acc[j] = v;
        m = fmaxf(m, v);
    }
    #pragma unroll
    for (int mask = 4; mask > 0; mask >>= 1) m = fmaxf(m, __shfl_xor(m, mask, 64));
    float sum = 0.0f;
    #pragma unroll
    for (int j = 0; j < 8; ++j) {
        float t = __expf(acc[j] - m);
        acc[j] = t;
        sum += t;
    }
    #pragma unroll
    for (int mask = 4; mask > 0; mask >>= 1) sum += __shfl_xor(sum, mask, 64);
    float inv = 1.0f / sum;
    if (sub == 0) {
        float* op = out + (size_t)n * 64 + c0;
        *(float4*)(op)     = make_float4(acc[0] * inv, acc[1] * inv, acc[2] * inv, acc[3] * inv);
        *(float4*)(op + 4) = make_float4(acc[4] * inv, acc[5] * inv, acc[6] * inv, acc[7] * inv);
    }
}

// ---------------- launch ----------------

extern "C" void kernel_launch(void* const* d_in, const int* in_sizes, int n_in,
                              void* d_out, int out_size, void* d_ws, size_t ws_size,
                              hipStream_t stream) {
    const float* x  = (const float*)d_in[0];
    const int*   ei = (const int*)d_in[1];
    const float* W1 = (const float*)d_in[2];
    const float* b1 = (const float*)d_in[3];
    const float* W2 = (const float*)d_in[4];
    const float* b2 = (const float*)d_in[5];
    const float* W3 = (const float*)d_in[6];
    const float* b3 = (const float*)d_in[7];
    const int* srcE = ei;
    const int* dstE = ei + N_EDGES;

    char* p = (char*)d_ws;
    auto carve = [&](size_t bytes) {
        char* q = p;
        p += (bytes + 255) & ~(size_t)255;
        return q;
    };
    int*          deg   = (int*)carve(sizeof(int) * N_NODES);
    int*          off   = (int*)carve(sizeof(int) * (N_NODES + 1));
    int*          cur   = (int*)carve(sizeof(int) * N_NODES);
    float*        dis   = (float*)carve(sizeof(float) * N_NODES);
    int*          bsum  = (int*)carve(sizeof(int) * 256);
    unsigned int* ed    = (unsigned int*)carve(sizeof(unsigned int) * N_EDGES);
    ushort_t*     ssort = (ushort_t*)carve(sizeof(ushort_t) * E_TOT);
    short*        w1h   = (short*)carve(sizeof(short) * 128 * 256);
    short*        w1l   = (short*)carve(sizeof(short) * 128 * 256);
    short*        w2h   = (short*)carve(sizeof(short) * 256 * 128);
    short*        w2l   = (short*)carve(sizeof(short) * 256 * 128);
    short*        w3h   = (short*)carve(sizeof(short) * 128 * 64);
    short*        w3l   = (short*)carve(sizeof(short) * 128 * 64);
    _Float16*     xh    = (_Float16*)carve(sizeof(_Float16) * (size_t)N_NODES * 128);
    _Float16*     a0h   = (_Float16*)carve(sizeof(_Float16) * (size_t)N_NODES * 128);
    _Float16*     x1h   = (_Float16*)carve(sizeof(_Float16) * (size_t)N_NODES * 256);
    _Float16*     x2h   = (_Float16*)carve(sizeof(_Float16) * (size_t)N_NODES * 128);
    _Float16*     hh    = (_Float16*)carve(sizeof(_Float16) * (size_t)N_NODES * 128);  // h2' then h3'

    k_init_deg<<<N_NODES / 256, 256, 0, stream>>>(deg);
    k_hist<<<(N_EDGES + 255) / 256, 256, 0, stream>>>(srcE, dstE, deg, ed);
    k_scan1<<<N_NODES / 256, 256, 0, stream>>>(deg, off, bsum);
    k_scan2<<<1, 256, 0, stream>>>(bsum);
    k_scan3<<<N_NODES / 256, 256, 0, stream>>>(deg, off, cur, dis, bsum);
    k_scatter<<<2048, 256, 0, stream>>>(ed, cur, ssort);
    k_convx<<<(N_NODES * 128 / 4) / 256, 256, 0, stream>>>(x, dis, xh);
    k_convw<<<(16 * 4 * 64 + 255) / 256, 256, 0, stream>>>(W1, 128, 256, w1h, w1l);
    k_convw<<<(8 * 8 * 64 + 255) / 256, 256, 0, stream>>>(W2, 256, 128, w2h, w2l);
    k_convw<<<(4 * 4 * 64 + 255) / 256, 256, 0, stream>>>(W3, 128, 64, w3h, w3l);

    // layer 1 (agg-first): a0[n] = dis[n] * sum xh[src]  (xh pre-scaled by dis[src]), fp16
    k_agg128h<false><<<N_NODES / 4, 256, 0, stream>>>(xh, off, ssort, dis, nullptr, a0h);
    // x1 = softmax(relu(a0@W1 + b1)), fp16
    k_mm<128, 256, true><<<N_NODES / 64, 256, 0, stream>>>(a0h, w1h, w1l, b1, nullptr, x1h);
    // layer 2: h2' = fp16(dis .* (x1@W2)); x2 = softmax(relu(dis[n]*segsum(h2') + b2)), fp16
    k_mm<256, 128, false><<<N_NODES / 64, 256, 0, stream>>>(x1h, w2h, w2l, nullptr, dis, hh);
    k_agg128h<true><<<N_NODES / 4, 256, 0, stream>>>(hh, off, ssort, dis, b2, x2h);
    // layer 3: h3' = fp16(dis .* (x2@W3)); out = softmax(relu(dis[n]*segsum(h3') + b3)), fp32
    k_mm<128, 64, false><<<N_NODES / 64, 256, 0, stream>>>(x2h, w3h, w3l, nullptr, dis, hh);
    k_agg64h<<<N_NODES / 4, 256, 0, stream>>>(hh, off, ssort, dis, b3, (float*)d_out);
}

// Round 9
// 400.013 us; speedup vs baseline: 1.3832x; 1.0070x over previous
//
#include <hip/hip_runtime.h>
#include <cstdint>
#include <cstddef>

#define N_NODES 65536
#define N_EDGES 1048576
#define E_TOT   (N_EDGES + N_NODES)
#define NSLICE  8192                    // N_NODES / 8 XCD slices
#define SCHUNK  ((E_TOT + 255) / 256)   // 4352: 256 chunks per slice
#define CPAD    16                      // pad atomic counters: 1 per 64B line

using short8  = __attribute__((ext_vector_type(8))) short;
using floatx4 = __attribute__((ext_vector_type(4))) float;
using half8   = __attribute__((ext_vector_type(8))) _Float16;
using half4   = __attribute__((ext_vector_type(4))) _Float16;
typedef unsigned short ushort_t;

// split fp32 -> bf16 hi (RTN) + bf16 lo (trunc of residual)
__device__ inline void split_bf16(float a, short& hi, short& lo) {
    unsigned u  = __float_as_uint(a);
    unsigned hr = (u + 0x7fffu + ((u >> 16) & 1u)) >> 16;
    float    hf = __uint_as_float(hr << 16);
    hi = (short)hr;
    float    lf = a - hf;
    lo = (short)(__float_as_uint(lf) >> 16);
}

// ---------------- preprocessing ----------------

__global__ void k_init_deg(int* __restrict__ deg) {
    int n = blockIdx.x * 256 + threadIdx.x;
    deg[(size_t)n * CPAD] = 1;  // self loop
}

// histogram (line-padded counters) + pack edges into (src<<16)|dst uint stream
__global__ void k_hist(const int* __restrict__ src, const int* __restrict__ dst,
                       int* __restrict__ deg, unsigned int* __restrict__ ed) {
    int e = blockIdx.x * 256 + threadIdx.x;
    if (e < N_EDGES) {
        int d = dst[e], s = src[e];
        ed[e] = (unsigned int)d | ((unsigned int)s << 16);
        atomicAdd(&deg[(size_t)d * CPAD], 1);
    }
}

__global__ __launch_bounds__(256) void k_scan1(const int* __restrict__ deg, int* __restrict__ off,
                                               int* __restrict__ bsum) {
    __shared__ int sb[256];
    int tid = threadIdx.x;
    int g = blockIdx.x * 256 + tid;
    int v = deg[(size_t)g * CPAD];
    sb[tid] = v;
    __syncthreads();
    #pragma unroll
    for (int s = 1; s < 256; s <<= 1) {
        int t = (tid >= s) ? sb[tid - s] : 0;
        __syncthreads();
        sb[tid] += t;
        __syncthreads();
    }
    off[g] = sb[tid] - v;
    if (tid == 255) bsum[blockIdx.x] = sb[255];
}

__global__ __launch_bounds__(256) void k_scan2(int* __restrict__ bsum) {
    __shared__ int sb[256];
    int tid = threadIdx.x;
    int v = bsum[tid];
    sb[tid] = v;
    __syncthreads();
    #pragma unroll
    for (int s = 1; s < 256; s <<= 1) {
        int t = (tid >= s) ? sb[tid - s] : 0;
        __syncthreads();
        sb[tid] += t;
        __syncthreads();
    }
    bsum[tid] = sb[tid] - v;
}

__global__ __launch_bounds__(256) void k_scan3(const int* __restrict__ deg, int* __restrict__ off,
                                               int* __restrict__ cursor, float* __restrict__ dis,
                                               const int* __restrict__ bsum) {
    int tid = threadIdx.x;
    int g = blockIdx.x * 256 + tid;
    int o = off[g] + bsum[blockIdx.x];
    off[g] = o;
    cursor[(size_t)g * CPAD] = o;
    dis[g] = rsqrtf((float)deg[(size_t)g * CPAD]);
    if (g == 0) off[N_NODES] = E_TOT;
}

// XCD-sliced counting-sort scatter: packed edge stream, ushort output, padded cursors
__global__ void k_scatter(const unsigned int* __restrict__ ed,
                          int* __restrict__ cursor, ushort_t* __restrict__ ssort) {
    int g   = blockIdx.x & 7;
    int blk = blockIdx.x >> 3;
    int lo = g * NSLICE, hi = lo + NSLICE;
    int e0 = blk * SCHUNK;
    int e1 = e0 + SCHUNK; if (e1 > E_TOT) e1 = E_TOT;
    for (int e = e0 + threadIdx.x; e < e1; e += 256) {
        int d, s;
        if (e < N_EDGES) { unsigned int v = ed[e]; d = (int)(v & 0xffffu); s = (int)(v >> 16); }
        else             { d = s = e - N_EDGES; }
        if (d >= lo && d < hi) {
            int pos = atomicAdd(&cursor[(size_t)d * CPAD], 1);
            ssort[pos] = (ushort_t)s;
        }
    }
}

// ---------------- x -> fp16 rows pre-scaled by dis[row] ----------------

__global__ __launch_bounds__(256) void k_convx(const float* __restrict__ x, const float* __restrict__ dis,
                                               _Float16* __restrict__ xh) {
    int g = blockIdx.x * 256 + threadIdx.x;   // group of 4 elements
    int idx = g * 4;
    int row = idx >> 7;
    float d = dis[row];
    float4 v = *(const float4*)(x + idx);
    half4 o = {(_Float16)(d * v.x), (_Float16)(d * v.y), (_Float16)(d * v.z), (_Float16)(d * v.w)};
    *(half4*)(xh + idx) = o;
}

// ---------------- W1,W2,W3 -> fragment-ordered bf16 hi/lo (single launch) ----------------

__device__ inline void convw_one(const float* W, int K, int N, short* Bh, short* Bl, int g) {
    int lane = g & 63;
    int kt = (g >> 6) % (K / 32);
    int nt = (g >> 6) / (K / 32);
    int n = nt * 16 + (lane & 15);
    int kbase = kt * 32 + (lane >> 4) * 8;
    #pragma unroll
    for (int j = 0; j < 8; ++j) {
        short h, l;
        split_bf16(W[(size_t)(kbase + j) * N + n], h, l);
        Bh[(size_t)g * 8 + j] = h;
        Bl[(size_t)g * 8 + j] = l;
    }
}

#define G1 (16 * 4 * 64)   // W1 128x256
#define G2 (8 * 8 * 64)    // W2 256x128
#define G3 (4 * 4 * 64)    // W3 128x64

__global__ void k_convw3(const float* __restrict__ W1, short* __restrict__ w1h, short* __restrict__ w1l,
                         const float* __restrict__ W2, short* __restrict__ w2h, short* __restrict__ w2l,
                         const float* __restrict__ W3, short* __restrict__ w3h, short* __restrict__ w3l) {
    int g = blockIdx.x * 256 + threadIdx.x;
    if (g < G1)            convw_one(W1, 128, 256, w1h, w1l, g);
    else if (g < G1 + G2)  convw_one(W2, 256, 128, w2h, w2l, g - G1);
    else if (g < G1 + G2 + G3) convw_one(W3, 128, 64, w3h, w3l, g - G1 - G2);
}

// ---------------- split-bf16 MFMA GEMM: C[M,N] = A[M,K] @ W ----------------
// A is fp16 rows. ACT: C = softmax(relu(C + bias)) -> fp16.
// else: C = dis[row] * C -> fp16 (feeds the gather).

template <int K, int N, bool ACT>
__global__ __launch_bounds__(256) void k_mm(const _Float16* __restrict__ A,
                                            const short* __restrict__ Bh, const short* __restrict__ Bl,
                                            const float* __restrict__ bias, const float* __restrict__ dis,
                                            _Float16* __restrict__ Cout) {
    constexpr int NT = N / 16;
    constexpr int KT = K / 32;
    __shared__ short Ah[4 * 64 * 8];
    __shared__ short Al[4 * 64 * 8];
    int tid = threadIdx.x;
    int wave = tid >> 6, lane = tid & 63;
    int quad = lane >> 4, col = lane & 15;
    size_t row0 = (size_t)blockIdx.x * 64;

    floatx4 acc[NT];
    #pragma unroll
    for (int t = 0; t < NT; ++t) acc[t] = (floatx4)0.0f;

    int srow = tid >> 2;
    int sdst = ((srow >> 4) * 64 + (srow & 15) + ((tid & 3) << 4)) * 8;
    const _Float16* arow = A + (row0 + srow) * K + (tid & 3) * 8;

    for (int kt = 0; kt < KT; ++kt) {
        half8 a8 = *(const half8*)(arow + kt * 32);
        short h[8], l[8];
        #pragma unroll
        for (int j = 0; j < 8; ++j) split_bf16((float)a8[j], h[j], l[j]);
        __syncthreads();
        *(short8*)(&Ah[sdst]) = *(short8*)h;
        *(short8*)(&Al[sdst]) = *(short8*)l;
        __syncthreads();
        short8 afh = *(short8*)(&Ah[(wave * 64 + lane) * 8]);
        short8 afl = *(short8*)(&Al[(wave * 64 + lane) * 8]);
        #pragma unroll
        for (int nt = 0; nt < NT; ++nt) {
            size_t bi = ((size_t)(nt * KT + kt) * 64 + lane);
            short8 bfh = ((const short8*)Bh)[bi];
            short8 bfl = ((const short8*)Bl)[bi];
            acc[nt] = __builtin_amdgcn_mfma_f32_16x16x32_bf16(afh, bfh, acc[nt], 0, 0, 0);
            acc[nt] = __builtin_amdgcn_mfma_f32_16x16x32_bf16(afh, bfl, acc[nt], 0, 0, 0);
            acc[nt] = __builtin_amdgcn_mfma_f32_16x16x32_bf16(afl, bfh, acc[nt], 0, 0, 0);
        }
    }

    size_t rbase = row0 + wave * 16 + quad * 4;
    if (!ACT) {
        float4 d4 = *(const float4*)(dis + rbase);
        float dr[4] = {d4.x, d4.y, d4.z, d4.w};
        #pragma unroll
        for (int nt = 0; nt < NT; ++nt)
            #pragma unroll
            for (int r = 0; r < 4; ++r)
                Cout[(rbase + r) * N + nt * 16 + col] = (_Float16)(acc[nt][r] * dr[r]);
    } else {
        float bv[NT];
        #pragma unroll
        for (int nt = 0; nt < NT; ++nt) bv[nt] = bias[nt * 16 + col];
        float mr[4] = {0.f, 0.f, 0.f, 0.f};
        #pragma unroll
        for (int nt = 0; nt < NT; ++nt)
            #pragma unroll
            for (int r = 0; r < 4; ++r) {
                float v = fmaxf(acc[nt][r] + bv[nt], 0.0f);
                acc[nt][r] = v;
                mr[r] = fmaxf(mr[r], v);
            }
        #pragma unroll
        for (int mask = 1; mask < 16; mask <<= 1)
            #pragma unroll
            for (int r = 0; r < 4; ++r) mr[r] = fmaxf(mr[r], __shfl_xor(mr[r], mask, 64));
        float sr[4] = {0.f, 0.f, 0.f, 0.f};
        #pragma unroll
        for (int nt = 0; nt < NT; ++nt)
            #pragma unroll
            for (int r = 0; r < 4; ++r) {
                float t = __expf(acc[nt][r] - mr[r]);
                acc[nt][r] = t;
                sr[r] += t;
            }
        #pragma unroll
        for (int mask = 1; mask < 16; mask <<= 1)
            #pragma unroll
            for (int r = 0; r < 4; ++r) sr[r] += __shfl_xor(sr[r], mask, 64);
        float inv[4];
        #pragma unroll
        for (int r = 0; r < 4; ++r) inv[r] = 1.0f / sr[r];
        #pragma unroll
        for (int nt = 0; nt < NT; ++nt)
            #pragma unroll
            for (int r = 0; r < 4; ++r)
                Cout[(rbase + r) * N + nt * 16 + col] = (_Float16)(acc[nt][r] * inv[r]);
    }
}

// ---------------- aggregation, DOUT=128, fp16 rows: quarter-wave (16 lanes x 16B) per edge ----------------

template <bool ACT>
__global__ __launch_bounds__(256) void k_agg128h(const _Float16* __restrict__ h, const int* __restrict__ off,
                                                 const ushort_t* __restrict__ ss, const float* __restrict__ dis,
                                                 const float* __restrict__ bias, _Float16* __restrict__ out) {
    int lane = threadIdx.x & 63;
    int sub = lane >> 4;      // 0..3: edge slot
    int li  = lane & 15;      // column group: halfs [li*8, li*8+8)
    int c0  = li * 8;
    int n = blockIdx.x * 4 + (threadIdx.x >> 6);
    int e0 = off[n], e1 = off[n + 1];
    int e = e0;
    float acc[8];
    #pragma unroll
    for (int j = 0; j < 8; ++j) acc[j] = 0.0f;

    for (; e + 8 <= e1; e += 8) {
        int sa = ss[e + sub];
        int sb = ss[e + 4 + sub];
        half8 va = *(const half8*)(h + (size_t)sa * 128 + c0);
        half8 vb = *(const half8*)(h + (size_t)sb * 128 + c0);
        #pragma unroll
        for (int j = 0; j < 8; ++j) acc[j] += (float)va[j] + (float)vb[j];
    }
    while (e < e1) {
        int rem = e1 - e;
        int idx = e + sub;
        if (idx >= e1) idx = e1 - 1;
        int s = ss[idx];
        half8 v = *(const half8*)(h + (size_t)s * 128 + c0);
        float w = (sub < rem) ? 1.0f : 0.0f;
        #pragma unroll
        for (int j = 0; j < 8; ++j) acc[j] = fmaf(w, (float)v[j], acc[j]);
        e += 4;
    }

    #pragma unroll
    for (int mask = 32; mask >= 16; mask >>= 1)
        #pragma unroll
        for (int j = 0; j < 8; ++j) acc[j] += __shfl_xor(acc[j], mask, 64);

    float dn = dis[n];
    if (ACT) {
        float m = 0.0f;
        #pragma unroll
        for (int j = 0; j < 8; ++j) {
            float v = fmaxf(fmaf(acc[j], dn, bias[c0 + j]), 0.0f);
            acc[j] = v;
            m = fmaxf(m, v);
        }
        #pragma unroll
        for (int mask = 8; mask > 0; mask >>= 1) m = fmaxf(m, __shfl_xor(m, mask, 64));
        float sum = 0.0f;
        #pragma unroll
        for (int j = 0; j < 8; ++j) {
            float t = __expf(acc[j] - m);
            acc[j] = t;
            sum += t;
        }
        #pragma unroll
        for (int mask = 8; mask > 0; mask >>= 1) sum += __shfl_xor(sum, mask, 64);
        float inv = 1.0f / sum;
        #pragma unroll
        for (int j = 0; j < 8; ++j) acc[j] *= inv;
    } else {
        #pragma unroll
        for (int j = 0; j < 8; ++j) acc[j] *= dn;
    }
    if (sub == 0) {
        half8 o;
        #pragma unroll
        for (int j = 0; j < 8; ++j) o[j] = (_Float16)acc[j];
        *(half8*)(out + (size_t)n * 128 + c0) = o;
    }
}

// ---------------- aggregation, DOUT=64, fp16 rows: eighth-wave (8 lanes x 16B) per edge ----------------

__global__ __launch_bounds__(256) void k_agg64h(const _Float16* __restrict__ h, const int* __restrict__ off,
                                                const ushort_t* __restrict__ ss, const float* __restrict__ dis,
                                                const float* __restrict__ bias, float* __restrict__ out) {
    int lane = threadIdx.x & 63;
    int sub = lane >> 3;      // 0..7: edge slot
    int li  = lane & 7;       // column group: halfs [li*8, li*8+8)
    int c0  = li * 8;
    int n = blockIdx.x * 4 + (threadIdx.x >> 6);
    int e0 = off[n], e1 = off[n + 1];
    int e = e0;
    float acc[8];
    #pragma unroll
    for (int j = 0; j < 8; ++j) acc[j] = 0.0f;

    for (; e + 8 <= e1; e += 8) {
        int s = ss[e + sub];
        half8 v = *(const half8*)(h + (size_t)s * 64 + c0);
        #pragma unroll
        for (int j = 0; j < 8; ++j) acc[j] += (float)v[j];
    }
    int rem = e1 - e;
    if (rem > 0) {
        int idx = e + sub;
        if (idx >= e1) idx = e1 - 1;
        int s = ss[idx];
        half8 v = *(const half8*)(h + (size_t)s * 64 + c0);
        float w = (sub < rem) ? 1.0f : 0.0f;
        #pragma unroll
        for (int j = 0; j < 8; ++j) acc[j] = fmaf(w, (float)v[j], acc[j]);
    }

    #pragma unroll
    for (int mask = 32; mask >= 8; mask >>= 1)
        #pragma unroll
        for (int j = 0; j < 8; ++j) acc[j] += __shfl_xor(acc[j], mask, 64);

    float dn = dis[n];
    float m = 0.0f;
    #pragma unroll
    for (int j = 0; j < 8; ++j) {
        float v = fmaxf(fmaf(acc[j], dn, bias[c0 + j]), 0.0f);
        acc[j] = v;
        m = fmaxf(m, v);
    }
    #pragma unroll
    for (int mask = 4; mask > 0; mask >>= 1) m = fmaxf(m, __shfl_xor(m, mask, 64));
    float sum = 0.0f;
    #pragma unroll
    for (int j = 0; j < 8; ++j) {
        float t = __expf(acc[j] - m);
        acc[j] = t;
        sum += t;
    }
    #pragma unroll
    for (int mask = 4; mask > 0; mask >>= 1) sum += __shfl_xor(sum, mask, 64);
    float inv = 1.0f / sum;
    if (sub == 0) {
        float* op = out + (size_t)n * 64 + c0;
        *(float4*)(op)     = make_float4(acc[0] * inv, acc[1] * inv, acc[2] * inv, acc[3] * inv);
        *(float4*)(op + 4) = make_float4(acc[4] * inv, acc[5] * inv, acc[6] * inv, acc[7] * inv);
    }
}

// ---------------- launch ----------------

extern "C" void kernel_launch(void* const* d_in, const int* in_sizes, int n_in,
                              void* d_out, int out_size, void* d_ws, size_t ws_size,
                              hipStream_t stream) {
    const float* x  = (const float*)d_in[0];
    const int*   ei = (const int*)d_in[1];
    const float* W1 = (const float*)d_in[2];
    const float* b1 = (const float*)d_in[3];
    const float* W2 = (const float*)d_in[4];
    const float* b2 = (const float*)d_in[5];
    const float* W3 = (const float*)d_in[6];
    const float* b3 = (const float*)d_in[7];
    const int* srcE = ei;
    const int* dstE = ei + N_EDGES;

    char* p = (char*)d_ws;
    auto carve = [&](size_t bytes) {
        char* q = p;
        p += (bytes + 255) & ~(size_t)255;
        return q;
    };
    int*          deg   = (int*)carve(sizeof(int) * N_NODES * CPAD);
    int*          cur   = (int*)carve(sizeof(int) * N_NODES * CPAD);
    int*          off   = (int*)carve(sizeof(int) * (N_NODES + 1));
    float*        dis   = (float*)carve(sizeof(float) * N_NODES);
    int*          bsum  = (int*)carve(sizeof(int) * 256);
    unsigned int* ed    = (unsigned int*)carve(sizeof(unsigned int) * N_EDGES);
    ushort_t*     ssort = (ushort_t*)carve(sizeof(ushort_t) * E_TOT);
    short*        w1h   = (short*)carve(sizeof(short) * 128 * 256);
    short*        w1l   = (short*)carve(sizeof(short) * 128 * 256);
    short*        w2h   = (short*)carve(sizeof(short) * 256 * 128);
    short*        w2l   = (short*)carve(sizeof(short) * 256 * 128);
    short*        w3h   = (short*)carve(sizeof(short) * 128 * 64);
    short*        w3l   = (short*)carve(sizeof(short) * 128 * 64);
    _Float16*     xh    = (_Float16*)carve(sizeof(_Float16) * (size_t)N_NODES * 128);
    _Float16*     a0h   = (_Float16*)carve(sizeof(_Float16) * (size_t)N_NODES * 128);
    _Float16*     x1h   = (_Float16*)carve(sizeof(_Float16) * (size_t)N_NODES * 256);
    _Float16*     x2h   = (_Float16*)carve(sizeof(_Float16) * (size_t)N_NODES * 128);
    _Float16*     hh    = (_Float16*)carve(sizeof(_Float16) * (size_t)N_NODES * 128);  // h2' then h3'

    k_init_deg<<<N_NODES / 256, 256, 0, stream>>>(deg);
    k_hist<<<(N_EDGES + 255) / 256, 256, 0, stream>>>(srcE, dstE, deg, ed);
    k_scan1<<<N_NODES / 256, 256, 0, stream>>>(deg, off, bsum);
    k_scan2<<<1, 256, 0, stream>>>(bsum);
    k_scan3<<<N_NODES / 256, 256, 0, stream>>>(deg, off, cur, dis, bsum);
    k_scatter<<<2048, 256, 0, stream>>>(ed, cur, ssort);
    k_convx<<<(N_NODES * 128 / 4) / 256, 256, 0, stream>>>(x, dis, xh);
    k_convw3<<<(G1 + G2 + G3 + 255) / 256, 256, 0, stream>>>(W1, w1h, w1l, W2, w2h, w2l, W3, w3h, w3l);

    // layer 1 (agg-first): a0[n] = dis[n] * sum xh[src]  (xh pre-scaled by dis[src]), fp16
    k_agg128h<false><<<N_NODES / 4, 256, 0, stream>>>(xh, off, ssort, dis, nullptr, a0h);
    // x1 = softmax(relu(a0@W1 + b1)), fp16
    k_mm<128, 256, true><<<N_NODES / 64, 256, 0, stream>>>(a0h, w1h, w1l, b1, nullptr, x1h);
    // layer 2: h2' = fp16(dis .* (x1@W2)); x2 = softmax(relu(dis[n]*segsum(h2') + b2)), fp16
    k_mm<256, 128, false><<<N_NODES / 64, 256, 0, stream>>>(x1h, w2h, w2l, nullptr, dis, hh);
    k_agg128h<true><<<N_NODES / 4, 256, 0, stream>>>(hh, off, ssort, dis, b2, x2h);
    // layer 3: h3' = fp16(dis .* (x2@W3)); out = softmax(relu(dis[n]*segsum(h3') + b3)), fp32
    k_mm<128, 64, false><<<N_NODES / 64, 256, 0, stream>>>(x2h, w3h, w3l, nullptr, dis, hh);
    k_agg64h<<<N_NODES / 4, 256, 0, stream>>>(hh, off, ssort, dis, b3, (float*)d_out);
}

// Round 10
// 397.140 us; speedup vs baseline: 1.3932x; 1.0072x over previous
//
#include <hip/hip_runtime.h>
#include <cstdint>
#include <cstddef>

#define N_NODES 65536
#define N_EDGES 1048576
#define E_TOT   (N_EDGES + N_NODES)
#define NSLICE  8192                    // N_NODES / 8 XCD slices
#define SCHUNK  ((E_TOT + 255) / 256)   // 4352: 256 chunks per slice

using short8  = __attribute__((ext_vector_type(8))) short;
using floatx4 = __attribute__((ext_vector_type(4))) float;
using half8   = __attribute__((ext_vector_type(8))) _Float16;
using half4   = __attribute__((ext_vector_type(4))) _Float16;
typedef unsigned short ushort_t;

// split fp32 -> bf16 hi (RTN) + bf16 lo (trunc of residual)
__device__ inline void split_bf16(float a, short& hi, short& lo) {
    unsigned u  = __float_as_uint(a);
    unsigned hr = (u + 0x7fffu + ((u >> 16) & 1u)) >> 16;
    float    hf = __uint_as_float(hr << 16);
    hi = (short)hr;
    float    lf = a - hf;
    lo = (short)(__float_as_uint(lf) >> 16);
}

// ---------------- preprocessing ----------------

__global__ void k_init_deg(int* __restrict__ deg) {
    int n = blockIdx.x * 256 + threadIdx.x;
    deg[n] = 1;  // self loop
}

// histogram + pack edges into (src<<16)|dst uint stream; nt loads keep L2 clean
__global__ void k_hist(const int* __restrict__ src, const int* __restrict__ dst,
                       int* __restrict__ deg, unsigned int* __restrict__ ed) {
    int e = blockIdx.x * 256 + threadIdx.x;
    if (e < N_EDGES) {
        int d = __builtin_nontemporal_load(&dst[e]);
        int s = __builtin_nontemporal_load(&src[e]);
        ed[e] = (unsigned int)d | ((unsigned int)s << 16);
        atomicAdd(&deg[d], 1);
    }
}

__global__ __launch_bounds__(256) void k_scan1(const int* __restrict__ deg, int* __restrict__ off,
                                               int* __restrict__ bsum) {
    __shared__ int sb[256];
    int tid = threadIdx.x;
    int g = blockIdx.x * 256 + tid;
    int v = deg[g];
    sb[tid] = v;
    __syncthreads();
    #pragma unroll
    for (int s = 1; s < 256; s <<= 1) {
        int t = (tid >= s) ? sb[tid - s] : 0;
        __syncthreads();
        sb[tid] += t;
        __syncthreads();
    }
    off[g] = sb[tid] - v;
    if (tid == 255) bsum[blockIdx.x] = sb[255];
}

__global__ __launch_bounds__(256) void k_scan2(int* __restrict__ bsum) {
    __shared__ int sb[256];
    int tid = threadIdx.x;
    int v = bsum[tid];
    sb[tid] = v;
    __syncthreads();
    #pragma unroll
    for (int s = 1; s < 256; s <<= 1) {
        int t = (tid >= s) ? sb[tid - s] : 0;
        __syncthreads();
        sb[tid] += t;
        __syncthreads();
    }
    bsum[tid] = sb[tid] - v;
}

__global__ __launch_bounds__(256) void k_scan3(const int* __restrict__ deg, int* __restrict__ off,
                                               int* __restrict__ cursor, float* __restrict__ dis,
                                               const int* __restrict__ bsum) {
    int tid = threadIdx.x;
    int g = blockIdx.x * 256 + tid;
    int o = off[g] + bsum[blockIdx.x];
    off[g] = o;
    cursor[g] = o;
    dis[g] = rsqrtf((float)deg[g]);
    if (g == 0) off[N_NODES] = E_TOT;
}

// XCD-sliced counting-sort scatter: packed edge stream via nt loads (no L2 pollution),
// ushort output. Dirty ssort/cursor lines stay L2-resident until full.
__global__ void k_scatter(const unsigned int* __restrict__ ed,
                          int* __restrict__ cursor, ushort_t* __restrict__ ssort) {
    int g   = blockIdx.x & 7;
    int blk = blockIdx.x >> 3;
    int lo = g * NSLICE, hi = lo + NSLICE;
    int e0 = blk * SCHUNK;
    int e1 = e0 + SCHUNK; if (e1 > E_TOT) e1 = E_TOT;
    for (int e = e0 + threadIdx.x; e < e1; e += 256) {
        int d, s;
        if (e < N_EDGES) {
            unsigned int v = __builtin_nontemporal_load(&ed[e]);
            d = (int)(v & 0xffffu);
            s = (int)(v >> 16);
        } else {
            d = s = e - N_EDGES;
        }
        if (d >= lo && d < hi) {
            int pos = atomicAdd(&cursor[d], 1);
            ssort[pos] = (ushort_t)s;
        }
    }
}

// ---------------- x -> fp16 rows pre-scaled by dis[row] ----------------

__global__ __launch_bounds__(256) void k_convx(const float* __restrict__ x, const float* __restrict__ dis,
                                               _Float16* __restrict__ xh) {
    int g = blockIdx.x * 256 + threadIdx.x;   // group of 4 elements
    int idx = g * 4;
    int row = idx >> 7;
    float d = dis[row];
    float4 v = *(const float4*)(x + idx);
    half4 o = {(_Float16)(d * v.x), (_Float16)(d * v.y), (_Float16)(d * v.z), (_Float16)(d * v.w)};
    *(half4*)(xh + idx) = o;
}

// ---------------- W1,W2,W3 -> fragment-ordered bf16 hi/lo (single launch) ----------------

__device__ inline void convw_one(const float* W, int K, int N, short* Bh, short* Bl, int g) {
    int lane = g & 63;
    int kt = (g >> 6) % (K / 32);
    int nt = (g >> 6) / (K / 32);
    int n = nt * 16 + (lane & 15);
    int kbase = kt * 32 + (lane >> 4) * 8;
    #pragma unroll
    for (int j = 0; j < 8; ++j) {
        short h, l;
        split_bf16(W[(size_t)(kbase + j) * N + n], h, l);
        Bh[(size_t)g * 8 + j] = h;
        Bl[(size_t)g * 8 + j] = l;
    }
}

#define G1 (16 * 4 * 64)   // W1 128x256
#define G2 (8 * 8 * 64)    // W2 256x128
#define G3 (4 * 4 * 64)    // W3 128x64

__global__ void k_convw3(const float* __restrict__ W1, short* __restrict__ w1h, short* __restrict__ w1l,
                         const float* __restrict__ W2, short* __restrict__ w2h, short* __restrict__ w2l,
                         const float* __restrict__ W3, short* __restrict__ w3h, short* __restrict__ w3l) {
    int g = blockIdx.x * 256 + threadIdx.x;
    if (g < G1)            convw_one(W1, 128, 256, w1h, w1l, g);
    else if (g < G1 + G2)  convw_one(W2, 256, 128, w2h, w2l, g - G1);
    else if (g < G1 + G2 + G3) convw_one(W3, 128, 64, w3h, w3l, g - G1 - G2);
}

// ---------------- split-bf16 MFMA GEMM: C[M,N] = A[M,K] @ W ----------------
// A is fp16 rows. ACT: C = softmax(relu(C + bias)) -> fp16.
// else: C = dis[row] * C -> fp16 (feeds the gather).

template <int K, int N, bool ACT>
__global__ __launch_bounds__(256) void k_mm(const _Float16* __restrict__ A,
                                            const short* __restrict__ Bh, const short* __restrict__ Bl,
                                            const float* __restrict__ bias, const float* __restrict__ dis,
                                            _Float16* __restrict__ Cout) {
    constexpr int NT = N / 16;
    constexpr int KT = K / 32;
    __shared__ short Ah[4 * 64 * 8];
    __shared__ short Al[4 * 64 * 8];
    int tid = threadIdx.x;
    int wave = tid >> 6, lane = tid & 63;
    int quad = lane >> 4, col = lane & 15;
    size_t row0 = (size_t)blockIdx.x * 64;

    floatx4 acc[NT];
    #pragma unroll
    for (int t = 0; t < NT; ++t) acc[t] = (floatx4)0.0f;

    int srow = tid >> 2;
    int sdst = ((srow >> 4) * 64 + (srow & 15) + ((tid & 3) << 4)) * 8;
    const _Float16* arow = A + (row0 + srow) * K + (tid & 3) * 8;

    for (int kt = 0; kt < KT; ++kt) {
        half8 a8 = *(const half8*)(arow + kt * 32);
        short h[8], l[8];
        #pragma unroll
        for (int j = 0; j < 8; ++j) split_bf16((float)a8[j], h[j], l[j]);
        __syncthreads();
        *(short8*)(&Ah[sdst]) = *(short8*)h;
        *(short8*)(&Al[sdst]) = *(short8*)l;
        __syncthreads();
        short8 afh = *(short8*)(&Ah[(wave * 64 + lane) * 8]);
        short8 afl = *(short8*)(&Al[(wave * 64 + lane) * 8]);
        #pragma unroll
        for (int nt = 0; nt < NT; ++nt) {
            size_t bi = ((size_t)(nt * KT + kt) * 64 + lane);
            short8 bfh = ((const short8*)Bh)[bi];
            short8 bfl = ((const short8*)Bl)[bi];
            acc[nt] = __builtin_amdgcn_mfma_f32_16x16x32_bf16(afh, bfh, acc[nt], 0, 0, 0);
            acc[nt] = __builtin_amdgcn_mfma_f32_16x16x32_bf16(afh, bfl, acc[nt], 0, 0, 0);
            acc[nt] = __builtin_amdgcn_mfma_f32_16x16x32_bf16(afl, bfh, acc[nt], 0, 0, 0);
        }
    }

    size_t rbase = row0 + wave * 16 + quad * 4;
    if (!ACT) {
        float4 d4 = *(const float4*)(dis + rbase);
        float dr[4] = {d4.x, d4.y, d4.z, d4.w};
        #pragma unroll
        for (int nt = 0; nt < NT; ++nt)
            #pragma unroll
            for (int r = 0; r < 4; ++r)
                Cout[(rbase + r) * N + nt * 16 + col] = (_Float16)(acc[nt][r] * dr[r]);
    } else {
        float bv[NT];
        #pragma unroll
        for (int nt = 0; nt < NT; ++nt) bv[nt] = bias[nt * 16 + col];
        float mr[4] = {0.f, 0.f, 0.f, 0.f};
        #pragma unroll
        for (int nt = 0; nt < NT; ++nt)
            #pragma unroll
            for (int r = 0; r < 4; ++r) {
                float v = fmaxf(acc[nt][r] + bv[nt], 0.0f);
                acc[nt][r] = v;
                mr[r] = fmaxf(mr[r], v);
            }
        #pragma unroll
        for (int mask = 1; mask < 16; mask <<= 1)
            #pragma unroll
            for (int r = 0; r < 4; ++r) mr[r] = fmaxf(mr[r], __shfl_xor(mr[r], mask, 64));
        float sr[4] = {0.f, 0.f, 0.f, 0.f};
        #pragma unroll
        for (int nt = 0; nt < NT; ++nt)
            #pragma unroll
            for (int r = 0; r < 4; ++r) {
                float t = __expf(acc[nt][r] - mr[r]);
                acc[nt][r] = t;
                sr[r] += t;
            }
        #pragma unroll
        for (int mask = 1; mask < 16; mask <<= 1)
            #pragma unroll
            for (int r = 0; r < 4; ++r) sr[r] += __shfl_xor(sr[r], mask, 64);
        float inv[4];
        #pragma unroll
        for (int r = 0; r < 4; ++r) inv[r] = 1.0f / sr[r];
        #pragma unroll
        for (int nt = 0; nt < NT; ++nt)
            #pragma unroll
            for (int r = 0; r < 4; ++r)
                Cout[(rbase + r) * N + nt * 16 + col] = (_Float16)(acc[nt][r] * inv[r]);
    }
}

// ---------------- aggregation, DOUT=128, fp16 rows: quarter-wave (16 lanes x 16B) per edge ----------------

template <bool ACT>
__global__ __launch_bounds__(256) void k_agg128h(const _Float16* __restrict__ h, const int* __restrict__ off,
                                                 const ushort_t* __restrict__ ss, const float* __restrict__ dis,
                                                 const float* __restrict__ bias, _Float16* __restrict__ out) {
    int lane = threadIdx.x & 63;
    int sub = lane >> 4;      // 0..3: edge slot
    int li  = lane & 15;      // column group: halfs [li*8, li*8+8)
    int c0  = li * 8;
    int n = blockIdx.x * 4 + (threadIdx.x >> 6);
    int e0 = off[n], e1 = off[n + 1];
    int e = e0;
    float acc[8];
    #pragma unroll
    for (int j = 0; j < 8; ++j) acc[j] = 0.0f;

    for (; e + 8 <= e1; e += 8) {
        int sa = ss[e + sub];
        int sb = ss[e + 4 + sub];
        half8 va = *(const half8*)(h + (size_t)sa * 128 + c0);
        half8 vb = *(const half8*)(h + (size_t)sb * 128 + c0);
        #pragma unroll
        for (int j = 0; j < 8; ++j) acc[j] += (float)va[j] + (float)vb[j];
    }
    while (e < e1) {
        int rem = e1 - e;
        int idx = e + sub;
        if (idx >= e1) idx = e1 - 1;
        int s = ss[idx];
        half8 v = *(const half8*)(h + (size_t)s * 128 + c0);
        float w = (sub < rem) ? 1.0f : 0.0f;
        #pragma unroll
        for (int j = 0; j < 8; ++j) acc[j] = fmaf(w, (float)v[j], acc[j]);
        e += 4;
    }

    #pragma unroll
    for (int mask = 32; mask >= 16; mask >>= 1)
        #pragma unroll
        for (int j = 0; j < 8; ++j) acc[j] += __shfl_xor(acc[j], mask, 64);

    float dn = dis[n];
    if (ACT) {
        float m = 0.0f;
        #pragma unroll
        for (int j = 0; j < 8; ++j) {
            float v = fmaxf(fmaf(acc[j], dn, bias[c0 + j]), 0.0f);
            acc[j] = v;
            m = fmaxf(m, v);
        }
        #pragma unroll
        for (int mask = 8; mask > 0; mask >>= 1) m = fmaxf(m, __shfl_xor(m, mask, 64));
        float sum = 0.0f;
        #pragma unroll
        for (int j = 0; j < 8; ++j) {
            float t = __expf(acc[j] - m);
            acc[j] = t;
            sum += t;
        }
        #pragma unroll
        for (int mask = 8; mask > 0; mask >>= 1) sum += __shfl_xor(sum, mask, 64);
        float inv = 1.0f / sum;
        #pragma unroll
        for (int j = 0; j < 8; ++j) acc[j] *= inv;
    } else {
        #pragma unroll
        for (int j = 0; j < 8; ++j) acc[j] *= dn;
    }
    if (sub == 0) {
        half8 o;
        #pragma unroll
        for (int j = 0; j < 8; ++j) o[j] = (_Float16)acc[j];
        *(half8*)(out + (size_t)n * 128 + c0) = o;
    }
}

// ---------------- aggregation, DOUT=64, fp16 rows: eighth-wave (8 lanes x 16B) per edge ----------------

__global__ __launch_bounds__(256) void k_agg64h(const _Float16* __restrict__ h, const int* __restrict__ off,
                                                const ushort_t* __restrict__ ss, const float* __restrict__ dis,
                                                const float* __restrict__ bias, float* __restrict__ out) {
    int lane = threadIdx.x & 63;
    int sub = lane >> 3;      // 0..7: edge slot
    int li  = lane & 7;       // column group: halfs [li*8, li*8+8)
    int c0  = li * 8;
    int n = blockIdx.x * 4 + (threadIdx.x >> 6);
    int e0 = off[n], e1 = off[n + 1];
    int e = e0;
    float acc[8];
    #pragma unroll
    for (int j = 0; j < 8; ++j) acc[j] = 0.0f;

    for (; e + 8 <= e1; e += 8) {
        int s = ss[e + sub];
        half8 v = *(const half8*)(h + (size_t)s * 64 + c0);
        #pragma unroll
        for (int j = 0; j < 8; ++j) acc[j] += (float)v[j];
    }
    int rem = e1 - e;
    if (rem > 0) {
        int idx = e + sub;
        if (idx >= e1) idx = e1 - 1;
        int s = ss[idx];
        half8 v = *(const half8*)(h + (size_t)s * 64 + c0);
        float w = (sub < rem) ? 1.0f : 0.0f;
        #pragma unroll
        for (int j = 0; j < 8; ++j) acc[j] = fmaf(w, (float)v[j], acc[j]);
    }

    #pragma unroll
    for (int mask = 32; mask >= 8; mask >>= 1)
        #pragma unroll
        for (int j = 0; j < 8; ++j) acc[j] += __shfl_xor(acc[j], mask, 64);

    float dn = dis[n];
    float m = 0.0f;
    #pragma unroll
    for (int j = 0; j < 8; ++j) {
        float v = fmaxf(fmaf(acc[j], dn, bias[c0 + j]), 0.0f);
        acc[j] = v;
        m = fmaxf(m, v);
    }
    #pragma unroll
    for (int mask = 4; mask > 0; mask >>= 1) m = fmaxf(m, __shfl_xor(m, mask, 64));
    float sum = 0.0f;
    #pragma unroll
    for (int j = 0; j < 8; ++j) {
        float t = __expf(acc[j] - m);
        acc[j] = t;
        sum += t;
    }
    #pragma unroll
    for (int mask = 4; mask > 0; mask >>= 1) sum += __shfl_xor(sum, mask, 64);
    float inv = 1.0f / sum;
    if (sub == 0) {
        float* op = out + (size_t)n * 64 + c0;
        *(float4*)(op)     = make_float4(acc[0] * inv, acc[1] * inv, acc[2] * inv, acc[3] * inv);
        *(float4*)(op + 4) = make_float4(acc[4] * inv, acc[5] * inv, acc[6] * inv, acc[7] * inv);
    }
}

// ---------------- launch ----------------

extern "C" void kernel_launch(void* const* d_in, const int* in_sizes, int n_in,
                              void* d_out, int out_size, void* d_ws, size_t ws_size,
                              hipStream_t stream) {
    const float* x  = (const float*)d_in[0];
    const int*   ei = (const int*)d_in[1];
    const float* W1 = (const float*)d_in[2];
    const float* b1 = (const float*)d_in[3];
    const float* W2 = (const float*)d_in[4];
    const float* b2 = (const float*)d_in[5];
    const float* W3 = (const float*)d_in[6];
    const float* b3 = (const float*)d_in[7];
    const int* srcE = ei;
    const int* dstE = ei + N_EDGES;

    char* p = (char*)d_ws;
    auto carve = [&](size_t bytes) {
        char* q = p;
        p += (bytes + 255) & ~(size_t)255;
        return q;
    };
    int*          deg   = (int*)carve(sizeof(int) * N_NODES);
    int*          cur   = (int*)carve(sizeof(int) * N_NODES);
    int*          off   = (int*)carve(sizeof(int) * (N_NODES + 1));
    float*        dis   = (float*)carve(sizeof(float) * N_NODES);
    int*          bsum  = (int*)carve(sizeof(int) * 256);
    unsigned int* ed    = (unsigned int*)carve(sizeof(unsigned int) * N_EDGES);
    ushort_t*     ssort = (ushort_t*)carve(sizeof(ushort_t) * E_TOT);
    short*        w1h   = (short*)carve(sizeof(short) * 128 * 256);
    short*        w1l   = (short*)carve(sizeof(short) * 128 * 256);
    short*        w2h   = (short*)carve(sizeof(short) * 256 * 128);
    short*        w2l   = (short*)carve(sizeof(short) * 256 * 128);
    short*        w3h   = (short*)carve(sizeof(short) * 128 * 64);
    short*        w3l   = (short*)carve(sizeof(short) * 128 * 64);
    _Float16*     xh    = (_Float16*)carve(sizeof(_Float16) * (size_t)N_NODES * 128);
    _Float16*     a0h   = (_Float16*)carve(sizeof(_Float16) * (size_t)N_NODES * 128);
    _Float16*     x1h   = (_Float16*)carve(sizeof(_Float16) * (size_t)N_NODES * 256);
    _Float16*     x2h   = (_Float16*)carve(sizeof(_Float16) * (size_t)N_NODES * 128);
    _Float16*     hh    = (_Float16*)carve(sizeof(_Float16) * (size_t)N_NODES * 128);  // h2' then h3'

    k_init_deg<<<N_NODES / 256, 256, 0, stream>>>(deg);
    k_hist<<<(N_EDGES + 255) / 256, 256, 0, stream>>>(srcE, dstE, deg, ed);
    k_scan1<<<N_NODES / 256, 256, 0, stream>>>(deg, off, bsum);
    k_scan2<<<1, 256, 0, stream>>>(bsum);
    k_scan3<<<N_NODES / 256, 256, 0, stream>>>(deg, off, cur, dis, bsum);
    k_scatter<<<2048, 256, 0, stream>>>(ed, cur, ssort);
    k_convx<<<(N_NODES * 128 / 4) / 256, 256, 0, stream>>>(x, dis, xh);
    k_convw3<<<(G1 + G2 + G3 + 255) / 256, 256, 0, stream>>>(W1, w1h, w1l, W2, w2h, w2l, W3, w3h, w3l);

    // layer 1 (agg-first): a0[n] = dis[n] * sum xh[src]  (xh pre-scaled by dis[src]), fp16
    k_agg128h<false><<<N_NODES / 4, 256, 0, stream>>>(xh, off, ssort, dis, nullptr, a0h);
    // x1 = softmax(relu(a0@W1 + b1)), fp16
    k_mm<128, 256, true><<<N_NODES / 64, 256, 0, stream>>>(a0h, w1h, w1l, b1, nullptr, x1h);
    // layer 2: h2' = fp16(dis .* (x1@W2)); x2 = softmax(relu(dis[n]*segsum(h2') + b2)), fp16
    k_mm<256, 128, false><<<N_NODES / 64, 256, 0, stream>>>(x1h, w2h, w2l, nullptr, dis, hh);
    k_agg128h<true><<<N_NODES / 4, 256, 0, stream>>>(hh, off, ssort, dis, b2, x2h);
    // layer 3: h3' = fp16(dis .* (x2@W3)); out = softmax(relu(dis[n]*segsum(h3') + b3)), fp32
    k_mm<128, 64, false><<<N_NODES / 64, 256, 0, stream>>>(x2h, w3h, w3l, nullptr, dis, hh);
    k_agg64h<<<N_NODES / 4, 256, 0, stream>>>(hh, off, ssort, dis, b3, (float*)d_out);
}